// Round 20
// baseline (2198.327 us; speedup 1.0000x reference)
//
#include <hip/hip_runtime.h>
#include <hip/hip_fp16.h>
#include <cstdint>
#include <math.h>

typedef _Float16 h2 __attribute__((ext_vector_type(2)));

__device__ __forceinline__ h2 f2h2(float a, float b) {
    h2 r; r.x = (_Float16)a; r.y = (_Float16)b; return r;
}
__device__ __forceinline__ float fdot2f(h2 a, h2 b, float c) {
    return __builtin_amdgcn_fdot2(a, b, c, false);
}

// ---------------------------------------------------------------------------
// Threefry-2x32-20, exactly as JAX lowers it.
// ---------------------------------------------------------------------------
__device__ __forceinline__ uint32_t rotl32(uint32_t x, uint32_t n) {
    return (x << n) | (x >> (32u - n));
}

__device__ __forceinline__ void tf2x32(uint32_t k0, uint32_t k1,
                                       uint32_t x0, uint32_t x1,
                                       uint32_t& o0, uint32_t& o1) {
    uint32_t k2 = k0 ^ k1 ^ 0x1BD11BDAu;
    x0 += k0; x1 += k1;
    x0 += x1; x1 = rotl32(x1, 13); x1 ^= x0;
    x0 += x1; x1 = rotl32(x1, 15); x1 ^= x0;
    x0 += x1; x1 = rotl32(x1, 26); x1 ^= x0;
    x0 += x1; x1 = rotl32(x1, 6);  x1 ^= x0;
    x0 += k1; x1 += k2 + 1u;
    x0 += x1; x1 = rotl32(x1, 17); x1 ^= x0;
    x0 += x1; x1 = rotl32(x1, 29); x1 ^= x0;
    x0 += x1; x1 = rotl32(x1, 16); x1 ^= x0;
    x0 += x1; x1 = rotl32(x1, 24); x1 ^= x0;
    x0 += k2; x1 += k0 + 2u;
    x0 += x1; x1 = rotl32(x1, 13); x1 ^= x0;
    x0 += x1; x1 = rotl32(x1, 15); x1 ^= x0;
    x0 += x1; x1 = rotl32(x1, 26); x1 ^= x0;
    x0 += x1; x1 = rotl32(x1, 6);  x1 ^= x0;
    x0 += k0; x1 += k1 + 3u;
    x0 += x1; x1 = rotl32(x1, 17); x1 ^= x0;
    x0 += x1; x1 = rotl32(x1, 29); x1 ^= x0;
    x0 += x1; x1 = rotl32(x1, 16); x1 ^= x0;
    x0 += x1; x1 = rotl32(x1, 24); x1 ^= x0;
    x0 += k1; x1 += k2 + 4u;
    x0 += x1; x1 = rotl32(x1, 13); x1 ^= x0;
    x0 += x1; x1 = rotl32(x1, 15); x1 ^= x0;
    x0 += x1; x1 = rotl32(x1, 26); x1 ^= x0;
    x0 += x1; x1 = rotl32(x1, 6);  x1 ^= x0;
    x0 += k2; x1 += k0 + 5u;
    o0 = x0; o1 = x1;
}

__device__ float gumbel_at(int n, int which, int N) {
    uint32_t a0, a1, b0, b1;
    tf2x32(0u, 42u, 0u, 2u, a0, a1);   // constant-folded by compiler
    tf2x32(0u, 42u, 1u, 3u, b0, b1);
    uint32_t gk0 = which ? a1 : a0;
    uint32_t gk1 = which ? b1 : b0;
    int half = N >> 1;
    uint32_t o0, o1, bits;
    if (n < half) { tf2x32(gk0, gk1, (uint32_t)n, (uint32_t)(n + half), o0, o1); bits = o0; }
    else          { tf2x32(gk0, gk1, (uint32_t)(n - half), (uint32_t)n, o0, o1); bits = o1; }
    float f = __uint_as_float((bits >> 9) | 0x3F800000u) - 1.0f;
    float u = fmaxf(1.17549435e-38f, f);
    return -logf(-logf(u));
}

__device__ __forceinline__ uint32_t fmono(float f) {
    uint32_t b = __float_as_uint(f);
    return (b & 0x80000000u) ? ~b : (b | 0x80000000u);
}
__device__ __forceinline__ float funmono(uint32_t u) {
    uint32_t b = (u & 0x80000000u) ? (u & 0x7FFFFFFFu) : ~u;
    return __uint_as_float(b);
}

#define NEGF (-1e9f)
#define ATTNGRID 2048  /* persistent attn blocks */

// ---------------------------------------------------------------------------
// CSR build
// ---------------------------------------------------------------------------
__global__ void k_hist(const int* __restrict__ dstp, int* __restrict__ deg, int E) {
    int e = blockIdx.x * 256 + threadIdx.x;
    if (e < E) atomicAdd(&deg[dstp[e]], 1);
}

__global__ void k_scan1(const int* __restrict__ deg, int* __restrict__ bsum, int N) {
    __shared__ int s[256];
    int i = blockIdx.x * 256 + threadIdx.x;
    s[threadIdx.x] = (i < N) ? deg[i] : 0;
    __syncthreads();
    for (int st = 128; st > 0; st >>= 1) {
        if (threadIdx.x < st) s[threadIdx.x] += s[threadIdx.x + st];
        __syncthreads();
    }
    if (threadIdx.x == 0) bsum[blockIdx.x] = s[0];
}

__global__ void k_scan2(int* __restrict__ bsum, int nb) {
    __shared__ int s[256];
    int i = threadIdx.x;
    int v = (i < nb) ? bsum[i] : 0;
    s[i] = v;
    __syncthreads();
    for (int st = 1; st < 256; st <<= 1) {
        int t = (i >= st) ? s[i - st] : 0;
        __syncthreads();
        s[i] += t;
        __syncthreads();
    }
    if (i < nb) bsum[i] = s[i] - v;  // exclusive
}

__global__ void k_scan3(const int* __restrict__ deg, const int* __restrict__ bsum,
                        int* __restrict__ rowptr, int* __restrict__ cursor, int N) {
    __shared__ int s[256];
    int i = blockIdx.x * 256 + threadIdx.x;
    int v = (i < N) ? deg[i] : 0;
    s[threadIdx.x] = v;
    __syncthreads();
    for (int st = 1; st < 256; st <<= 1) {
        int t = (threadIdx.x >= st) ? s[threadIdx.x - st] : 0;
        __syncthreads();
        s[threadIdx.x] += t;
        __syncthreads();
    }
    int excl = s[threadIdx.x] - v + bsum[blockIdx.x];
    if (i < N) { rowptr[i] = excl; cursor[i] = excl; }
}

__global__ void k_fill(const int* __restrict__ dstp, const int* __restrict__ srcp,
                       const float* __restrict__ lat, int* __restrict__ cursor,
                       int2* __restrict__ srclat, int E) {
    int e = blockIdx.x * 256 + threadIdx.x;
    if (e < E) {
        int pos = atomicAdd(&cursor[dstp[e]], 1);
        srclat[pos] = make_int2(srcp[e], __float_as_int(lat[e]));
    }
}

// ---------------------------------------------------------------------------
// k_qkvr: batched GEMV via fp16 dot2 (fp32 accum). Weights in LDS as half2
// d-pairs (~37 KB -> 4 blocks/CU; grid 1024 exposes it). BN fused into
// x-staging. Outputs FP16: Q (128h), interleaved KV (256h), R (128h).
// ---------------------------------------------------------------------------
__global__ __launch_bounds__(512, 4) void k_qkvr(
        const float* __restrict__ xin, const float* __restrict__ nt,
        const float* __restrict__ rq, int din, int N,
        const float* __restrict__ Wq, const float* __restrict__ bq,
        const float* __restrict__ Wk, const float* __restrict__ bk,
        const float* __restrict__ Wv, const float* __restrict__ bv,
        const float* __restrict__ Ws, const float* __restrict__ bs,
        const double* __restrict__ SUM, const double* __restrict__ SUMSQ,
        const float* __restrict__ bng, const float* __restrict__ bnb,
        int applyBN,
        __half* __restrict__ Q, __half* __restrict__ KV, __half* __restrict__ R) {
    __shared__ h2 w2[4][16 * 128];     // 32 KB max
    __shared__ float bias[4][128];
    __shared__ h2 xs2[32][17];
    __shared__ float sscale[32], sshift[32];
    int t = threadIdx.x;
    int dpCount = din >> 1;            // 16 or 1
    for (int i = t; i < dpCount * 128; i += 512) {
        int dp = i >> 7, j = i & 127;
        w2[0][i] = f2h2(Wq[(size_t)(2 * dp) * 128 + j], Wq[(size_t)(2 * dp + 1) * 128 + j]);
        w2[1][i] = f2h2(Wk[(size_t)(2 * dp) * 128 + j], Wk[(size_t)(2 * dp + 1) * 128 + j]);
        w2[2][i] = f2h2(Wv[(size_t)(2 * dp) * 128 + j], Wv[(size_t)(2 * dp + 1) * 128 + j]);
        w2[3][i] = f2h2(Ws[(size_t)(2 * dp) * 128 + j], Ws[(size_t)(2 * dp + 1) * 128 + j]);
    }
    if (t < 128) {
        bias[0][t] = bq[t]; bias[1][t] = bk[t]; bias[2][t] = bv[t]; bias[3][t] = bs[t];
    }
    if (t < 32) {
        if (applyBN) {
            double m = SUM[t] / N;
            double v = SUMSQ[t] / N - m * m;
            float inv = rsqrtf((float)v + 1e-5f);
            float sc = inv * bng[t];
            sscale[t] = sc;
            sshift[t] = bnb[t] - (float)m * sc;
        } else {
            sscale[t] = 1.f; sshift[t] = 0.f;
        }
    }
    int quad = t & 31;
    int sub = t >> 5;   // 0..15, two nodes each
    int dpsh = (din == 32) ? 4 : 0;
    int tiles = (N + 31) >> 5;
    for (int tile = blockIdx.x; tile < tiles; tile += gridDim.x) {
        int base = tile << 5;
        __syncthreads();
        for (int i = t; i < 32 * dpCount; i += 512) {
            int nl = i >> dpsh, dp = i & (dpCount - 1);
            int nn = base + nl;
            float x0 = 0.f, x1 = 0.f;
            if (nn < N) {
                if (din == 2) { x0 = nt[nn]; x1 = rq[nn]; }
                else {
                    x0 = xin[(size_t)nn * din + 2 * dp];
                    x1 = xin[(size_t)nn * din + 2 * dp + 1];
                }
            }
            x0 = x0 * sscale[2 * dp] + sshift[2 * dp];
            x1 = x1 * sscale[2 * dp + 1] + sshift[2 * dp + 1];
            xs2[nl][dp] = f2h2(x0, x1);
        }
        __syncthreads();
        float acc[4][2][4];  // [mat][node][comp]
#pragma unroll
        for (int m = 0; m < 4; ++m)
#pragma unroll
            for (int k = 0; k < 2; ++k)
#pragma unroll
                for (int c = 0; c < 4; ++c) acc[m][k][c] = bias[m][quad * 4 + c];
        for (int dp = 0; dp < dpCount; ++dp) {
            h2 xv0 = xs2[sub * 2 + 0][dp];
            h2 xv1 = xs2[sub * 2 + 1][dp];
#pragma unroll
            for (int m = 0; m < 4; ++m) {
                const h2* wp = &w2[m][dp * 128 + quad * 4];
                h2 wa = wp[0], wb = wp[1], wc = wp[2], wd = wp[3];
                acc[m][0][0] = fdot2f(xv0, wa, acc[m][0][0]);
                acc[m][0][1] = fdot2f(xv0, wb, acc[m][0][1]);
                acc[m][0][2] = fdot2f(xv0, wc, acc[m][0][2]);
                acc[m][0][3] = fdot2f(xv0, wd, acc[m][0][3]);
                acc[m][1][0] = fdot2f(xv1, wa, acc[m][1][0]);
                acc[m][1][1] = fdot2f(xv1, wb, acc[m][1][1]);
                acc[m][1][2] = fdot2f(xv1, wc, acc[m][1][2]);
                acc[m][1][3] = fdot2f(xv1, wd, acc[m][1][3]);
            }
        }
#pragma unroll
        for (int k = 0; k < 2; ++k) {
            int n = base + sub * 2 + k;
            if (n < N) {
                *(__half2*)&Q[(size_t)n * 128 + quad * 4 + 0] =
                    __floats2half2_rn(acc[0][k][0], acc[0][k][1]);
                *(__half2*)&Q[(size_t)n * 128 + quad * 4 + 2] =
                    __floats2half2_rn(acc[0][k][2], acc[0][k][3]);
                *(__half2*)&KV[(size_t)n * 256 + quad * 4 + 0] =
                    __floats2half2_rn(acc[1][k][0], acc[1][k][1]);
                *(__half2*)&KV[(size_t)n * 256 + quad * 4 + 2] =
                    __floats2half2_rn(acc[1][k][2], acc[1][k][3]);
                *(__half2*)&KV[(size_t)n * 256 + 128 + quad * 4 + 0] =
                    __floats2half2_rn(acc[2][k][0], acc[2][k][1]);
                *(__half2*)&KV[(size_t)n * 256 + 128 + quad * 4 + 2] =
                    __floats2half2_rn(acc[2][k][2], acc[2][k][3]);
                *(__half2*)&R[(size_t)n * 128 + quad * 4 + 0] =
                    __floats2half2_rn(acc[3][k][0], acc[3][k][1]);
                *(__half2*)&R[(size_t)n * 128 + quad * 4 + 2] =
                    __floats2half2_rn(acc[3][k][2], acc[3][k][3]);
            }
        }
    }
}

// ---------------------------------------------------------------------------
// k_attn: persistent, wave-independent striding, fp16 dot2, algebraic We
// folding, fused GEMV. FUSED stat reduction: per-block partial row + done
// counter; last block reduces all ATTNGRID rows into SUM/SUMSQ and re-arms.
// ---------------------------------------------------------------------------
__global__ __launch_bounds__(256) void k_attn(
        const int2* __restrict__ srclat,
        const __half* __restrict__ Q, const __half* __restrict__ KV,
        const float* __restrict__ We,
        const __half* __restrict__ R, const float* __restrict__ Wb,
        const float* __restrict__ tW, const float* __restrict__ tb,
        const int* __restrict__ rowptr, const int* __restrict__ deg,
        float* __restrict__ H32, double* __restrict__ partials,
        double* __restrict__ SUM, double* __restrict__ SUMSQ,
        int* __restrict__ counter, int N) {
    __shared__ h2 wt2[64 * 32];        // 8 KB
    __shared__ float tbias[32];
    __shared__ h2 aLds2[4][66];
    __shared__ double sp1[4][32], sp2[4][32];
    __shared__ double red[4][64];
    __shared__ int isLast;
    int t = threadIdx.x;
    for (int i = t; i < 64 * 32; i += 256) {
        int dp = i >> 5, j = i & 31;
        wt2[i] = f2h2(tW[(size_t)(2 * dp) * 32 + j], tW[(size_t)(2 * dp + 1) * 32 + j]);
    }
    if (t < 32) tbias[t] = tb[t];
    __syncthreads();

    int wvid = t >> 6;
    int l64 = t & 63;
    int slot = l64 >> 5;
    int lane = l64 & 31;
    const float4 we4 = *(const float4*)&We[lane * 4];
    h2 weh0 = f2h2(we4.x, we4.y), weh1 = f2h2(we4.z, we4.w);
    const float4 wb0 = *(const float4*)&Wb[lane * 4];
    const float4 wb1 = *(const float4*)&Wb[128 + lane * 4];
    const float4 wb2 = *(const float4*)&Wb[256 + lane * 4];
    h2 zeroH; zeroH.x = (_Float16)0.f; zeroH.y = (_Float16)0.f;

    double s1 = 0.0, s2 = 0.0;

    int waveGlobal = blockIdx.x * 4 + wvid;
    int totalWaves = gridDim.x * 4;
    for (int n = waveGlobal; n < N; n += totalWaves) {
        const h2* qp = (const h2*)(Q + (size_t)n * 128 + lane * 4);
        h2 qh0 = qp[0], qh1 = qp[1];
        float qwe = fdot2f(qh0, weh0, fdot2f(qh1, weh1, 0.f));
        qwe += __shfl_xor(qwe, 1); qwe += __shfl_xor(qwe, 2); qwe += __shfl_xor(qwe, 4);

        int start = rowptr[n];
        int d = deg[n];

        float m = -INFINITY, den = 0.f, plsum = 0.f;
        float nx = 0.f, ny = 0.f, nz = 0.f, nw = 0.f;

        int idx = slot;
        bool have = idx < d;
        float l0 = 0.f;
        h2 k0a = zeroH, k0b = zeroH, v0a = zeroH, v0b = zeroH;
        if (have) {
            int2 sl = srclat[start + idx];
            l0 = __int_as_float(sl.y);
            const h2* kp = (const h2*)(KV + (size_t)sl.x * 256 + lane * 4);
            const h2* vp = (const h2*)(KV + (size_t)sl.x * 256 + 128 + lane * 4);
            k0a = kp[0]; k0b = kp[1]; v0a = vp[0]; v0b = vp[1];
        }
        while (have) {
            int idx2 = idx + 2;
            bool have2 = idx2 < d;
            float l1 = 0.f;
            h2 k1a = zeroH, k1b = zeroH, v1a = zeroH, v1b = zeroH;
            if (have2) {
                int2 sl = srclat[start + idx2];
                l1 = __int_as_float(sl.y);
                const h2* kp = (const h2*)(KV + (size_t)sl.x * 256 + lane * 4);
                const h2* vp = (const h2*)(KV + (size_t)sl.x * 256 + 128 + lane * 4);
                k1a = kp[0]; k1b = kp[1]; v1a = vp[0]; v1b = vp[1];
            }

            float t0 = fdot2f(qh0, k0a, fdot2f(qh1, k0b, 0.f));
            t0 += __shfl_xor(t0, 1); t0 += __shfl_xor(t0, 2); t0 += __shfl_xor(t0, 4);
            float alpha = fmaf(l0, qwe, t0) * 0.17677669529663687f;

            float mn = fmaxf(m, alpha);
            float sc = __expf(m - mn);
            float p = __expf(alpha - mn);
            nx = nx * sc + p * (float)v0a.x;
            ny = ny * sc + p * (float)v0a.y;
            nz = nz * sc + p * (float)v0b.x;
            nw = nw * sc + p * (float)v0b.y;
            plsum = plsum * sc + p * l0;
            den = den * sc + p;
            m = mn;

            idx = idx2; l0 = l1;
            k0a = k1a; k0b = k1b; v0a = v1a; v0b = v1b;
            have = have2;
        }

        float mo = __shfl_xor(m, 32);
        float mf = fmaxf(m, mo);
        float myscale = (m == -INFINITY) ? 0.f : __expf(m - mf);
        nx *= myscale; ny *= myscale; nz *= myscale; nw *= myscale;
        den *= myscale; plsum *= myscale;
        nx += __shfl_xor(nx, 32); ny += __shfl_xor(ny, 32);
        nz += __shfl_xor(nz, 32); nw += __shfl_xor(nw, 32);
        den += __shfl_xor(den, 32); plsum += __shfl_xor(plsum, 32);
        float inv = 1.f / (den + 1e-16f);
        float ox = fmaf(plsum, we4.x, nx) * inv;
        float oy = fmaf(plsum, we4.y, ny) * inv;
        float oz = fmaf(plsum, we4.z, nz) * inv;
        float ow = fmaf(plsum, we4.w, nw) * inv;

        const __half2* rp = (const __half2*)(R + (size_t)n * 128 + lane * 4);
        float2 ra = __half22float2(rp[0]), rb = __half22float2(rp[1]);
        float g = ox * wb0.x + ra.x * wb1.x + (ox - ra.x) * wb2.x
                + oy * wb0.y + ra.y * wb1.y + (oy - ra.y) * wb2.y
                + oz * wb0.z + rb.x * wb1.z + (oz - rb.x) * wb2.z
                + ow * wb0.w + rb.y * wb1.w + (ow - rb.y) * wb2.w;
        g += __shfl_xor(g, 1); g += __shfl_xor(g, 2); g += __shfl_xor(g, 4);
        g += __shfl_xor(g, 8); g += __shfl_xor(g, 16);
        float beta = 1.0f / (1.0f + __expf(-g));

        if (slot == 0) {
            float a0 = beta * ra.x + (1.0f - beta) * ox;
            float a1 = beta * ra.y + (1.0f - beta) * oy;
            float a2 = beta * rb.x + (1.0f - beta) * oz;
            float a3 = beta * rb.y + (1.0f - beta) * ow;
            aLds2[wvid][lane * 2 + 0] = f2h2(a0, a1);
            aLds2[wvid][lane * 2 + 1] = f2h2(a2, a3);
        }
        __builtin_amdgcn_wave_barrier();

        float acc = (slot == 0) ? tbias[lane] : 0.f;
        int dpb = slot * 32;
#pragma unroll 8
        for (int i = 0; i < 32; ++i) {
            int dp = dpb + i;
            acc = fdot2f(aLds2[wvid][dp], wt2[dp * 32 + lane], acc);
        }
        acc += __shfl_xor(acc, 32);
        float y = fmaxf(acc, 0.f);
        if (slot == 0) {
            H32[(size_t)n * 32 + lane] = y;
            s1 += (double)y; s2 += (double)y * y;
        }
        __builtin_amdgcn_wave_barrier();
    }

    if (slot == 0) { sp1[wvid][lane] = s1; sp2[wvid][lane] = s2; }
    __syncthreads();
    if (t < 32) {
        double a1 = sp1[0][t] + sp1[1][t] + sp1[2][t] + sp1[3][t];
        double a2 = sp2[0][t] + sp2[1][t] + sp2[2][t] + sp2[3][t];
        partials[(size_t)blockIdx.x * 64 + t] = a1;
        partials[(size_t)blockIdx.x * 64 + 32 + t] = a2;
    }
    // last-block reduction (grid unchanged; 2047 blocks just atomic+exit)
    __threadfence();
    if (t == 0) {
        int old = atomicAdd(counter, 1);
        isLast = (old == (int)gridDim.x - 1) ? 1 : 0;
    }
    __syncthreads();
    if (isLast) {
        __threadfence();
        int col = t & 63, chunk = t >> 6;
        double a = 0;
        for (int bidx = chunk; bidx < (int)gridDim.x; bidx += 4)
            a += partials[(size_t)bidx * 64 + col];
        red[chunk][col] = a;
        __syncthreads();
        if (t < 64) {
            double s = red[0][t] + red[1][t] + red[2][t] + red[3][t];
            if (t < 32) SUM[t] = s; else SUMSQ[t - 32] = s;
        }
        if (t == 0) atomicExch(counter, 0);  // re-arm for next layer
    }
}

// ---------------------------------------------------------------------------
// k_mlp1: BN affine + 32->128 relu. Block 0 zero-inits head scratch.
// ---------------------------------------------------------------------------
__global__ __launch_bounds__(256) void k_mlp1(
        const float* __restrict__ H32,
        const double* __restrict__ SUM, const double* __restrict__ SUMSQ,
        const float* __restrict__ bng, const float* __restrict__ bnb,
        const float* __restrict__ W1, const float* __restrict__ b1,
        float* __restrict__ Y1, unsigned int* __restrict__ smallbuf, int N) {
    __shared__ float w1[32 * 128];
    __shared__ float sb1[128];
    __shared__ float sscale[32], sshift[32];
    __shared__ float xs[32][36];
    int t = threadIdx.x;
    if (blockIdx.x == 0 && t < 16) smallbuf[t] = 0u;  // zero 64 B head scratch
    for (int i = t; i < 32 * 128; i += 256) w1[i] = W1[i];
    if (t < 128) sb1[t] = b1[t];
    if (t < 32) {
        double m = SUM[t] / N;
        double v = SUMSQ[t] / N - m * m;
        float inv = rsqrtf((float)v + 1e-5f);
        float sc = inv * bng[t];
        sscale[t] = sc;
        sshift[t] = bnb[t] - (float)m * sc;
    }
    int quad = t & 31, sub = t >> 5;
    int tiles = (N + 31) >> 5;
    for (int tile = blockIdx.x; tile < tiles; tile += gridDim.x) {
        int base = tile << 5;
        __syncthreads();
        {
            int nl = t >> 3, q = t & 7;
            int n = base + nl;
            float4 xv = make_float4(0.f, 0.f, 0.f, 0.f);
            if (n < N) xv = *(const float4*)&H32[(size_t)n * 32 + q * 4];
            xs[nl][q * 4 + 0] = xv.x * sscale[q * 4 + 0] + sshift[q * 4 + 0];
            xs[nl][q * 4 + 1] = xv.y * sscale[q * 4 + 1] + sshift[q * 4 + 1];
            xs[nl][q * 4 + 2] = xv.z * sscale[q * 4 + 2] + sshift[q * 4 + 2];
            xs[nl][q * 4 + 3] = xv.w * sscale[q * 4 + 3] + sshift[q * 4 + 3];
        }
        __syncthreads();
        float a[4][4];
#pragma unroll
        for (int k = 0; k < 4; ++k)
#pragma unroll
            for (int c = 0; c < 4; ++c) a[k][c] = sb1[quad * 4 + c];
        for (int d = 0; d < 32; ++d) {
            float4 w4 = *(const float4*)&w1[d * 128 + quad * 4];
#pragma unroll
            for (int k = 0; k < 4; ++k) {
                float x = xs[sub * 4 + k][d];
                a[k][0] = fmaf(x, w4.x, a[k][0]);
                a[k][1] = fmaf(x, w4.y, a[k][1]);
                a[k][2] = fmaf(x, w4.z, a[k][2]);
                a[k][3] = fmaf(x, w4.w, a[k][3]);
            }
        }
#pragma unroll
        for (int k = 0; k < 4; ++k) {
            int n = base + sub * 4 + k;
            if (n < N) {
                float4 yv;
                yv.x = fmaxf(a[k][0], 0.f); yv.y = fmaxf(a[k][1], 0.f);
                yv.z = fmaxf(a[k][2], 0.f); yv.w = fmaxf(a[k][3], 0.f);
                *(float4*)&Y1[(size_t)n * 128 + quad * 4] = yv;
            }
        }
    }
}

// ---------------------------------------------------------------------------
// k_mlp2: 128->64 relu.
// ---------------------------------------------------------------------------
__global__ __launch_bounds__(256) void k_mlp2(
        const float* __restrict__ Y1, const float* __restrict__ W2,
        const float* __restrict__ b2, float* __restrict__ Y2, int N) {
    __shared__ float w2f[128 * 64];
    __shared__ float sb2[64];
    __shared__ float xs[32][132];
    int t = threadIdx.x;
    for (int i = t; i < 128 * 64; i += 256) w2f[i] = W2[i];
    if (t < 64) sb2[t] = b2[t];
    int quad = t & 15, sub = t >> 4;
    int tiles = (N + 31) >> 5;
    for (int tile = blockIdx.x; tile < tiles; tile += gridDim.x) {
        int base = tile << 5;
        __syncthreads();
#pragma unroll
        for (int k = 0; k < 4; ++k) {
            int i = t + 256 * k;
            int nl = i >> 5, q = i & 31;
            int n = base + nl;
            float4 xv = make_float4(0.f, 0.f, 0.f, 0.f);
            if (n < N) xv = *(const float4*)&Y1[(size_t)n * 128 + q * 4];
            *(float4*)&xs[nl][q * 4] = xv;
        }
        __syncthreads();
        float a[2][4];
#pragma unroll
        for (int k = 0; k < 2; ++k)
#pragma unroll
            for (int c = 0; c < 4; ++c) a[k][c] = sb2[quad * 4 + c];
        for (int d = 0; d < 128; ++d) {
            float4 w4 = *(const float4*)&w2f[d * 64 + quad * 4];
#pragma unroll
            for (int k = 0; k < 2; ++k) {
                float x = xs[sub * 2 + k][d];
                a[k][0] = fmaf(x, w4.x, a[k][0]);
                a[k][1] = fmaf(x, w4.y, a[k][1]);
                a[k][2] = fmaf(x, w4.z, a[k][2]);
                a[k][3] = fmaf(x, w4.w, a[k][3]);
            }
        }
#pragma unroll
        for (int k = 0; k < 2; ++k) {
            int n = base + sub * 2 + k;
            if (n < N) {
                float4 yv;
                yv.x = fmaxf(a[k][0], 0.f); yv.y = fmaxf(a[k][1], 0.f);
                yv.z = fmaxf(a[k][2], 0.f); yv.w = fmaxf(a[k][3], 0.f);
                *(float4*)&Y2[(size_t)n * 64 + quad * 4] = yv;
            }
        }
    }
}

// ---------------------------------------------------------------------------
// k_mlp3: 64->64 (no relu), pure GEMV.
// ---------------------------------------------------------------------------
__global__ __launch_bounds__(256) void k_mlp3(
        const float* __restrict__ Y2, const float* __restrict__ W3,
        const float* __restrict__ b3, float* __restrict__ X3, int N) {
    __shared__ float w3[64 * 64];
    __shared__ float sb3[64];
    __shared__ float xs[32][68];
    int t = threadIdx.x;
    for (int i = t; i < 64 * 64; i += 256) w3[i] = W3[i];
    if (t < 64) sb3[t] = b3[t];
    int quad = t & 15, sub = t >> 4;
    int tiles = (N + 31) >> 5;
    for (int tile = blockIdx.x; tile < tiles; tile += gridDim.x) {
        int base = tile << 5;
        __syncthreads();
#pragma unroll
        for (int k = 0; k < 2; ++k) {
            int i = t + 256 * k;
            int nl = i >> 4, q = i & 15;
            int n = base + nl;
            float4 xv = make_float4(0.f, 0.f, 0.f, 0.f);
            if (n < N) xv = *(const float4*)&Y2[(size_t)n * 64 + q * 4];
            *(float4*)&xs[nl][q * 4] = xv;
        }
        __syncthreads();
        float a[2][4];
#pragma unroll
        for (int k = 0; k < 2; ++k)
#pragma unroll
            for (int c = 0; c < 4; ++c) a[k][c] = sb3[quad * 4 + c];
        for (int d = 0; d < 64; ++d) {
            float4 w4 = *(const float4*)&w3[d * 64 + quad * 4];
#pragma unroll
            for (int k = 0; k < 2; ++k) {
                float x = xs[sub * 2 + k][d];
                a[k][0] = fmaf(x, w4.x, a[k][0]);
                a[k][1] = fmaf(x, w4.y, a[k][1]);
                a[k][2] = fmaf(x, w4.z, a[k][2]);
                a[k][3] = fmaf(x, w4.w, a[k][3]);
            }
        }
#pragma unroll
        for (int k = 0; k < 2; ++k) {
            int n = base + sub * 2 + k;
            if (n < N)
                *(float4*)&X3[(size_t)n * 64 + quad * 4] = *(float4*)a[k];
        }
    }
}

// ---------------------------------------------------------------------------
// Head kernels
// ---------------------------------------------------------------------------
__global__ void k_head1(const float* __restrict__ X3, const float* __restrict__ remW,
                        const float* __restrict__ remB, const int* __restrict__ active,
                        float* __restrict__ l1out, unsigned long long* __restrict__ slot1,
                        unsigned int* __restrict__ m1, int N) {
    int n = blockIdx.x * 256 + threadIdx.x;
    if (n >= N) return;
    const float* xr = X3 + (size_t)n * 64;
    float acc = remB[0];
    for (int d = 0; d < 64; d++) acc = fmaf(xr[d], remW[d], acc);
    float maskf = (active[n] == 1) ? 0.f : NEGF;
    float rm = (n < 15) ? ((maskf == 0.f) ? NEGF : 0.f) : maskf;
    float l1 = acc + rm;
    l1out[n] = l1;
    atomicMax(m1, fmono(l1));
    float z = l1 + gumbel_at(n, 0, N);
    unsigned long long p = ((unsigned long long)fmono(z) << 32) |
                           (unsigned long long)(0xFFFFFFFFu - (unsigned)n);
    atomicMax(slot1, p);
}

__global__ void k_head2(const float* __restrict__ X3, const float* __restrict__ addW,
                        const float* __restrict__ addB,
                        const unsigned long long* __restrict__ slot1,
                        float* __restrict__ tvec, int* __restrict__ a1buf) {
    int j = threadIdx.x;  // 64
    unsigned long long p = *slot1;
    int a1 = (int)(0xFFFFFFFFu - (unsigned)(p & 0xFFFFFFFFull));
    const float* xr = X3 + (size_t)a1 * 64;
    float acc = addB[j];
    for (int d = 0; d < 64; d++) acc = fmaf(xr[d], addW[d * 64 + j], acc);
    tvec[j] = tanhf(acc);
    if (j == 0) *a1buf = a1;
}

__global__ void k_head3(const float* __restrict__ X3, const float* __restrict__ tvec,
                        const int* __restrict__ active, const int* __restrict__ a1buf,
                        float* __restrict__ l2out, unsigned long long* __restrict__ slot2,
                        unsigned int* __restrict__ m2, int N) {
    int n = blockIdx.x * 256 + threadIdx.x;
    if (n >= N) return;
    const float* xr = X3 + (size_t)n * 64;
    float acc = 0.f;
    for (int d = 0; d < 64; d++) acc = fmaf(xr[d], tvec[d], acc);
    float maskf = (active[n] == 1) ? 0.f : NEGF;
    if (n == *a1buf) maskf = 0.f;
    float l2 = acc + maskf;
    l2out[n] = l2;
    atomicMax(m2, fmono(l2));
    float z = l2 + gumbel_at(n, 1, N);
    unsigned long long p = ((unsigned long long)fmono(z) << 32) |
                           (unsigned long long)(0xFFFFFFFFu - (unsigned)n);
    atomicMax(slot2, p);
}

__global__ void k_sumexp(const float* __restrict__ l1, const float* __restrict__ l2,
                         const unsigned int* __restrict__ m1, const unsigned int* __restrict__ m2,
                         float* __restrict__ se, int N) {
    int t = blockIdx.x * 256 + threadIdx.x;
    float M1 = funmono(*m1), M2 = funmono(*m2);
    float e1 = 0.f, e2 = 0.f;
    if (t < N) { e1 = expf(l1[t] - M1); e2 = expf(l2[t] - M2); }
    __shared__ float r1[256], r2[256];
    r1[threadIdx.x] = e1; r2[threadIdx.x] = e2;
    __syncthreads();
    for (int s = 128; s > 0; s >>= 1) {
        if (threadIdx.x < s) { r1[threadIdx.x] += r1[threadIdx.x + s]; r2[threadIdx.x] += r2[threadIdx.x + s]; }
        __syncthreads();
    }
    if (threadIdx.x == 0) { atomicAdd(&se[0], r1[0]); atomicAdd(&se[1], r2[0]); }
}

__global__ void k_final(const float* __restrict__ l1, const float* __restrict__ l2,
                        const unsigned long long* __restrict__ slot2,
                        const int* __restrict__ a1buf,
                        const unsigned int* __restrict__ m1, const unsigned int* __restrict__ m2,
                        const float* __restrict__ se, float* __restrict__ outTail, int N) {
    int a1 = *a1buf;
    int a2 = (int)(0xFFFFFFFFu - (unsigned)((*slot2) & 0xFFFFFFFFull));
    outTail[0] = (float)a1;
    outTail[1] = (float)a2;
    outTail[2] = l1[a1] - (funmono(*m1) + logf(se[0]));
    outTail[3] = l2[a2] - (funmono(*m2) + logf(se[1]));
}

// ---------------------------------------------------------------------------
// Host launcher
// ---------------------------------------------------------------------------
extern "C" void kernel_launch(void* const* d_in, const int* in_sizes, int n_in,
                              void* d_out, int out_size, void* d_ws, size_t ws_size,
                              hipStream_t stream) {
    const float* node_type = (const float*)d_in[0];
    const float* requests  = (const float*)d_in[1];
    const float* latency   = (const float*)d_in[2];
    const int* edge_index  = (const int*)d_in[3];
    const int* active      = (const int*)d_in[4];
    int N = in_sizes[0];
    int E = in_sizes[2];
    const int* src = edge_index;
    const int* dst = edge_index + E;
    float* out = (float*)d_out;

    char* base = (char*)d_ws;
    size_t off = 0;
    auto alloc = [&](size_t bytes) -> char* {
        char* p = base + off;
        off += (bytes + 255) & ~(size_t)255;
        return p;
    };
    char* Abuf   = alloc((size_t)N * 128 * 4);  // fp32 Y2 (MLP stage)
    char* Qbuf   = alloc((size_t)N * 128 * 4);  // fp16 Q; later fp32 Y1
    __half* KV   = (__half*)alloc((size_t)N * 256 * 2); // interleaved K,V fp16
    char* Rbuf   = alloc((size_t)N * 128 * 4);  // fp16 R; later fp32 X3
    float* H32   = (float*)alloc((size_t)N * 32 * 4);
    int* deg     = (int*)alloc((size_t)N * 4 + 64);  // + done-counter tail
    int* counter = deg + N;
    int* rowptr  = (int*)alloc((size_t)N * 4);
    int* cursor  = (int*)alloc((size_t)N * 4);
    int2* srclat = (int2*)alloc((size_t)E * 8);
    int* bsum    = (int*)alloc(1024 * 4);
    double* partials = (double*)alloc((size_t)ATTNGRID * 64 * 8);
    double* SUM  = (double*)alloc(512);
    double* SUMSQ = SUM + 32;
    char* small  = alloc(1024);
    unsigned long long* slot1 = (unsigned long long*)small;
    unsigned long long* slot2 = slot1 + 1;
    unsigned int* m1 = (unsigned int*)(small + 16);
    unsigned int* m2 = m1 + 1;
    float* se = (float*)(small + 24);
    int* a1buf = (int*)(small + 32);
    float* tvec = (float*)(small + 64);

    __half* Qh = (__half*)Qbuf;   float* Y1f = (float*)Qbuf;
    __half* Rh = (__half*)Rbuf;   float* X3f = (float*)Rbuf;
    float* Y2f = (float*)Abuf;

    int ng = (N + 255) / 256;
    int egE = (E + 255) / 256;
    int nb = ng;

    // ---- CSR build (memset also zeroes the attn done-counter) ----
    (void)hipMemsetAsync(deg, 0, (size_t)N * 4 + 64, stream);
    k_hist<<<egE, 256, 0, stream>>>(dst, deg, E);
    k_scan1<<<nb, 256, 0, stream>>>(deg, bsum, N);
    k_scan2<<<1, 256, 0, stream>>>(bsum, nb);
    k_scan3<<<nb, 256, 0, stream>>>(deg, bsum, rowptr, cursor, N);
    k_fill<<<egE, 256, 0, stream>>>(dst, src, latency, cursor, srclat, E);

    for (int L = 0; L < 5; ++L) {
        int din = L ? 32 : 2;
        const float* xin = L ? H32 : nullptr;
        const float* Wq = L ? (const float*)d_in[19] + (size_t)(L - 1) * 4096 : (const float*)d_in[5];
        const float* bq = L ? (const float*)d_in[20] + (size_t)(L - 1) * 128  : (const float*)d_in[6];
        const float* Wk = L ? (const float*)d_in[21] + (size_t)(L - 1) * 4096 : (const float*)d_in[7];
        const float* bk = L ? (const float*)d_in[22] + (size_t)(L - 1) * 128  : (const float*)d_in[8];
        const float* Wv = L ? (const float*)d_in[23] + (size_t)(L - 1) * 4096 : (const float*)d_in[9];
        const float* bv = L ? (const float*)d_in[24] + (size_t)(L - 1) * 128  : (const float*)d_in[10];
        const float* We = L ? (const float*)d_in[25] + (size_t)(L - 1) * 128  : (const float*)d_in[11];
        const float* Ws = L ? (const float*)d_in[26] + (size_t)(L - 1) * 4096 : (const float*)d_in[12];
        const float* bs = L ? (const float*)d_in[27] + (size_t)(L - 1) * 128  : (const float*)d_in[13];
        const float* Wb = L ? (const float*)d_in[28] + (size_t)(L - 1) * 384  : (const float*)d_in[14];
        const float* tW = L ? (const float*)d_in[29] + (size_t)(L - 1) * 4096 : (const float*)d_in[15];
        const float* tb = L ? (const float*)d_in[30] + (size_t)(L - 1) * 32   : (const float*)d_in[16];
        const float* bngP = (L == 1) ? (const float*)d_in[17]
                          : (L >= 2) ? (const float*)d_in[31] + (size_t)(L - 2) * 32 : nullptr;
        const float* bnbP = (L == 1) ? (const float*)d_in[18]
                          : (L >= 2) ? (const float*)d_in[32] + (size_t)(L - 2) * 32 : nullptr;

        k_qkvr<<<1024, 512, 0, stream>>>(xin, node_type, requests, din, N,
                                         Wq, bq, Wk, bk, Wv, bv, Ws, bs,
                                         SUM, SUMSQ, bngP, bnbP, (L > 0) ? 1 : 0,
                                         Qh, KV, Rh);
        k_attn<<<ATTNGRID, 256, 0, stream>>>(srclat, Qh, KV, We, Rh, Wb,
                                             tW, tb, rowptr, deg,
                                             H32, partials, SUM, SUMSQ,
                                             counter, N);
    }

    // embedding MLP (split for occupancy): H32 -> Y1(Qbuf) -> Y2(Abuf) -> X3(Rbuf)
    k_mlp1<<<512, 256, 0, stream>>>(H32, SUM, SUMSQ,
                                    (const float*)d_in[31] + 3 * 32,
                                    (const float*)d_in[32] + 3 * 32,
                                    (const float*)d_in[33], (const float*)d_in[34],
                                    Y1f, (unsigned int*)small, N);
    k_mlp2<<<512, 256, 0, stream>>>(Y1f, (const float*)d_in[35], (const float*)d_in[36],
                                    Y2f, N);
    k_mlp3<<<512, 256, 0, stream>>>(Y2f, (const float*)d_in[37], (const float*)d_in[38],
                                    X3f, N);
    // head
    k_head1<<<ng, 256, 0, stream>>>(X3f, (const float*)d_in[39], (const float*)d_in[40],
                                    active, out, slot1, m1, N);
    k_head2<<<1, 64, 0, stream>>>(X3f, (const float*)d_in[41], (const float*)d_in[42],
                                  slot1, tvec, a1buf);
    k_head3<<<ng, 256, 0, stream>>>(X3f, tvec, active, a1buf, out + N, slot2, m2, N);
    k_sumexp<<<ng, 256, 0, stream>>>(out, out + N, m1, m2, se, N);
    k_final<<<1, 1, 0, stream>>>(out, out + N, slot2, a1buf, m1, m2, se, out + 2 * N, N);
}

// Round 21
// 845.365 us; speedup vs baseline: 2.6004x; 2.6004x over previous
//
#include <hip/hip_runtime.h>
#include <hip/hip_fp16.h>
#include <cstdint>
#include <math.h>

typedef _Float16 h2 __attribute__((ext_vector_type(2)));

__device__ __forceinline__ h2 f2h2(float a, float b) {
    h2 r; r.x = (_Float16)a; r.y = (_Float16)b; return r;
}
__device__ __forceinline__ float fdot2f(h2 a, h2 b, float c) {
    return __builtin_amdgcn_fdot2(a, b, c, false);
}

// ---------------------------------------------------------------------------
// Threefry-2x32-20, exactly as JAX lowers it.
// ---------------------------------------------------------------------------
__device__ __forceinline__ uint32_t rotl32(uint32_t x, uint32_t n) {
    return (x << n) | (x >> (32u - n));
}

__device__ __forceinline__ void tf2x32(uint32_t k0, uint32_t k1,
                                       uint32_t x0, uint32_t x1,
                                       uint32_t& o0, uint32_t& o1) {
    uint32_t k2 = k0 ^ k1 ^ 0x1BD11BDAu;
    x0 += k0; x1 += k1;
    x0 += x1; x1 = rotl32(x1, 13); x1 ^= x0;
    x0 += x1; x1 = rotl32(x1, 15); x1 ^= x0;
    x0 += x1; x1 = rotl32(x1, 26); x1 ^= x0;
    x0 += x1; x1 = rotl32(x1, 6);  x1 ^= x0;
    x0 += k1; x1 += k2 + 1u;
    x0 += x1; x1 = rotl32(x1, 17); x1 ^= x0;
    x0 += x1; x1 = rotl32(x1, 29); x1 ^= x0;
    x0 += x1; x1 = rotl32(x1, 16); x1 ^= x0;
    x0 += x1; x1 = rotl32(x1, 24); x1 ^= x0;
    x0 += k2; x1 += k0 + 2u;
    x0 += x1; x1 = rotl32(x1, 13); x1 ^= x0;
    x0 += x1; x1 = rotl32(x1, 15); x1 ^= x0;
    x0 += x1; x1 = rotl32(x1, 26); x1 ^= x0;
    x0 += x1; x1 = rotl32(x1, 6);  x1 ^= x0;
    x0 += k0; x1 += k1 + 3u;
    x0 += x1; x1 = rotl32(x1, 17); x1 ^= x0;
    x0 += x1; x1 = rotl32(x1, 29); x1 ^= x0;
    x0 += x1; x1 = rotl32(x1, 16); x1 ^= x0;
    x0 += x1; x1 = rotl32(x1, 24); x1 ^= x0;
    x0 += k1; x1 += k2 + 4u;
    x0 += x1; x1 = rotl32(x1, 13); x1 ^= x0;
    x0 += x1; x1 = rotl32(x1, 15); x1 ^= x0;
    x0 += x1; x1 = rotl32(x1, 26); x1 ^= x0;
    x0 += x1; x1 = rotl32(x1, 6);  x1 ^= x0;
    x0 += k2; x1 += k0 + 5u;
    o0 = x0; o1 = x1;
}

__device__ float gumbel_at(int n, int which, int N) {
    uint32_t a0, a1, b0, b1;
    tf2x32(0u, 42u, 0u, 2u, a0, a1);   // constant-folded by compiler
    tf2x32(0u, 42u, 1u, 3u, b0, b1);
    uint32_t gk0 = which ? a1 : a0;
    uint32_t gk1 = which ? b1 : b0;
    int half = N >> 1;
    uint32_t o0, o1, bits;
    if (n < half) { tf2x32(gk0, gk1, (uint32_t)n, (uint32_t)(n + half), o0, o1); bits = o0; }
    else          { tf2x32(gk0, gk1, (uint32_t)(n - half), (uint32_t)n, o0, o1); bits = o1; }
    float f = __uint_as_float((bits >> 9) | 0x3F800000u) - 1.0f;
    float u = fmaxf(1.17549435e-38f, f);
    return -logf(-logf(u));
}

__device__ __forceinline__ uint32_t fmono(float f) {
    uint32_t b = __float_as_uint(f);
    return (b & 0x80000000u) ? ~b : (b | 0x80000000u);
}
__device__ __forceinline__ float funmono(uint32_t u) {
    uint32_t b = (u & 0x80000000u) ? (u & 0x7FFFFFFFu) : ~u;
    return __uint_as_float(b);
}

#define NEGF (-1e9f)
#define SRBLK 128      /* stage-1 stat-reduce blocks */
#define ATTNGRID 2048  /* persistent attn blocks */

// ---------------------------------------------------------------------------
// CSR build
// ---------------------------------------------------------------------------
__global__ void k_hist(const int* __restrict__ dstp, int* __restrict__ deg, int E) {
    int e = blockIdx.x * 256 + threadIdx.x;
    if (e < E) atomicAdd(&deg[dstp[e]], 1);
}

__global__ void k_scan1(const int* __restrict__ deg, int* __restrict__ bsum, int N) {
    __shared__ int s[256];
    int i = blockIdx.x * 256 + threadIdx.x;
    s[threadIdx.x] = (i < N) ? deg[i] : 0;
    __syncthreads();
    for (int st = 128; st > 0; st >>= 1) {
        if (threadIdx.x < st) s[threadIdx.x] += s[threadIdx.x + st];
        __syncthreads();
    }
    if (threadIdx.x == 0) bsum[blockIdx.x] = s[0];
}

__global__ void k_scan2(int* __restrict__ bsum, int nb) {
    __shared__ int s[256];
    int i = threadIdx.x;
    int v = (i < nb) ? bsum[i] : 0;
    s[i] = v;
    __syncthreads();
    for (int st = 1; st < 256; st <<= 1) {
        int t = (i >= st) ? s[i - st] : 0;
        __syncthreads();
        s[i] += t;
        __syncthreads();
    }
    if (i < nb) bsum[i] = s[i] - v;  // exclusive
}

__global__ void k_scan3(const int* __restrict__ deg, const int* __restrict__ bsum,
                        int* __restrict__ rowptr, int* __restrict__ cursor, int N) {
    __shared__ int s[256];
    int i = blockIdx.x * 256 + threadIdx.x;
    int v = (i < N) ? deg[i] : 0;
    s[threadIdx.x] = v;
    __syncthreads();
    for (int st = 1; st < 256; st <<= 1) {
        int t = (threadIdx.x >= st) ? s[threadIdx.x - st] : 0;
        __syncthreads();
        s[threadIdx.x] += t;
        __syncthreads();
    }
    int excl = s[threadIdx.x] - v + bsum[blockIdx.x];
    if (i < N) { rowptr[i] = excl; cursor[i] = excl; }
}

__global__ void k_fill(const int* __restrict__ dstp, const int* __restrict__ srcp,
                       const float* __restrict__ lat, int* __restrict__ cursor,
                       int2* __restrict__ srclat, int E) {
    int e = blockIdx.x * 256 + threadIdx.x;
    if (e < E) {
        int pos = atomicAdd(&cursor[dstp[e]], 1);
        srclat[pos] = make_int2(srcp[e], __float_as_int(lat[e]));
    }
}

// ---------------------------------------------------------------------------
// k_qkvr: batched GEMV via fp16 dot2 (fp32 accum). Weights in LDS as half2
// d-pairs (~37 KB -> 4 blocks/CU; grid 1024 exposes it). BN fused into
// x-staging. Outputs FP16: Q (128h), interleaved KV (256h), R (128h).
// ---------------------------------------------------------------------------
__global__ __launch_bounds__(512, 4) void k_qkvr(
        const float* __restrict__ xin, const float* __restrict__ nt,
        const float* __restrict__ rq, int din, int N,
        const float* __restrict__ Wq, const float* __restrict__ bq,
        const float* __restrict__ Wk, const float* __restrict__ bk,
        const float* __restrict__ Wv, const float* __restrict__ bv,
        const float* __restrict__ Ws, const float* __restrict__ bs,
        const double* __restrict__ SUM, const double* __restrict__ SUMSQ,
        const float* __restrict__ bng, const float* __restrict__ bnb,
        int applyBN,
        __half* __restrict__ Q, __half* __restrict__ KV, __half* __restrict__ R) {
    __shared__ h2 w2[4][16 * 128];     // 32 KB max
    __shared__ float bias[4][128];
    __shared__ h2 xs2[32][17];
    __shared__ float sscale[32], sshift[32];
    int t = threadIdx.x;
    int dpCount = din >> 1;            // 16 or 1
    for (int i = t; i < dpCount * 128; i += 512) {
        int dp = i >> 7, j = i & 127;
        w2[0][i] = f2h2(Wq[(size_t)(2 * dp) * 128 + j], Wq[(size_t)(2 * dp + 1) * 128 + j]);
        w2[1][i] = f2h2(Wk[(size_t)(2 * dp) * 128 + j], Wk[(size_t)(2 * dp + 1) * 128 + j]);
        w2[2][i] = f2h2(Wv[(size_t)(2 * dp) * 128 + j], Wv[(size_t)(2 * dp + 1) * 128 + j]);
        w2[3][i] = f2h2(Ws[(size_t)(2 * dp) * 128 + j], Ws[(size_t)(2 * dp + 1) * 128 + j]);
    }
    if (t < 128) {
        bias[0][t] = bq[t]; bias[1][t] = bk[t]; bias[2][t] = bv[t]; bias[3][t] = bs[t];
    }
    if (t < 32) {
        if (applyBN) {
            double m = SUM[t] / N;
            double v = SUMSQ[t] / N - m * m;
            float inv = rsqrtf((float)v + 1e-5f);
            float sc = inv * bng[t];
            sscale[t] = sc;
            sshift[t] = bnb[t] - (float)m * sc;
        } else {
            sscale[t] = 1.f; sshift[t] = 0.f;
        }
    }
    int quad = t & 31;
    int sub = t >> 5;   // 0..15, two nodes each
    int dpsh = (din == 32) ? 4 : 0;
    int tiles = (N + 31) >> 5;
    for (int tile = blockIdx.x; tile < tiles; tile += gridDim.x) {
        int base = tile << 5;
        __syncthreads();
        for (int i = t; i < 32 * dpCount; i += 512) {
            int nl = i >> dpsh, dp = i & (dpCount - 1);
            int nn = base + nl;
            float x0 = 0.f, x1 = 0.f;
            if (nn < N) {
                if (din == 2) { x0 = nt[nn]; x1 = rq[nn]; }
                else {
                    x0 = xin[(size_t)nn * din + 2 * dp];
                    x1 = xin[(size_t)nn * din + 2 * dp + 1];
                }
            }
            x0 = x0 * sscale[2 * dp] + sshift[2 * dp];
            x1 = x1 * sscale[2 * dp + 1] + sshift[2 * dp + 1];
            xs2[nl][dp] = f2h2(x0, x1);
        }
        __syncthreads();
        float acc[4][2][4];  // [mat][node][comp]
#pragma unroll
        for (int m = 0; m < 4; ++m)
#pragma unroll
            for (int k = 0; k < 2; ++k)
#pragma unroll
                for (int c = 0; c < 4; ++c) acc[m][k][c] = bias[m][quad * 4 + c];
        for (int dp = 0; dp < dpCount; ++dp) {
            h2 xv0 = xs2[sub * 2 + 0][dp];
            h2 xv1 = xs2[sub * 2 + 1][dp];
#pragma unroll
            for (int m = 0; m < 4; ++m) {
                const h2* wp = &w2[m][dp * 128 + quad * 4];
                h2 wa = wp[0], wb = wp[1], wc = wp[2], wd = wp[3];
                acc[m][0][0] = fdot2f(xv0, wa, acc[m][0][0]);
                acc[m][0][1] = fdot2f(xv0, wb, acc[m][0][1]);
                acc[m][0][2] = fdot2f(xv0, wc, acc[m][0][2]);
                acc[m][0][3] = fdot2f(xv0, wd, acc[m][0][3]);
                acc[m][1][0] = fdot2f(xv1, wa, acc[m][1][0]);
                acc[m][1][1] = fdot2f(xv1, wb, acc[m][1][1]);
                acc[m][1][2] = fdot2f(xv1, wc, acc[m][1][2]);
                acc[m][1][3] = fdot2f(xv1, wd, acc[m][1][3]);
            }
        }
#pragma unroll
        for (int k = 0; k < 2; ++k) {
            int n = base + sub * 2 + k;
            if (n < N) {
                *(__half2*)&Q[(size_t)n * 128 + quad * 4 + 0] =
                    __floats2half2_rn(acc[0][k][0], acc[0][k][1]);
                *(__half2*)&Q[(size_t)n * 128 + quad * 4 + 2] =
                    __floats2half2_rn(acc[0][k][2], acc[0][k][3]);
                *(__half2*)&KV[(size_t)n * 256 + quad * 4 + 0] =
                    __floats2half2_rn(acc[1][k][0], acc[1][k][1]);
                *(__half2*)&KV[(size_t)n * 256 + quad * 4 + 2] =
                    __floats2half2_rn(acc[1][k][2], acc[1][k][3]);
                *(__half2*)&KV[(size_t)n * 256 + 128 + quad * 4 + 0] =
                    __floats2half2_rn(acc[2][k][0], acc[2][k][1]);
                *(__half2*)&KV[(size_t)n * 256 + 128 + quad * 4 + 2] =
                    __floats2half2_rn(acc[2][k][2], acc[2][k][3]);
                *(__half2*)&R[(size_t)n * 128 + quad * 4 + 0] =
                    __floats2half2_rn(acc[3][k][0], acc[3][k][1]);
                *(__half2*)&R[(size_t)n * 128 + quad * 4 + 2] =
                    __floats2half2_rn(acc[3][k][2], acc[3][k][3]);
            }
        }
    }
}

// ---------------------------------------------------------------------------
// k_attn: persistent, wave-independent striding. fp16 dot2 QK; l*We folded
// out algebraically; fused GEMV in half2. NO device-scope fences (stat
// reduction is done by separate kernels — inter-dispatch barrier is free).
// ---------------------------------------------------------------------------
__global__ __launch_bounds__(256) void k_attn(
        const int2* __restrict__ srclat,
        const __half* __restrict__ Q, const __half* __restrict__ KV,
        const float* __restrict__ We,
        const __half* __restrict__ R, const float* __restrict__ Wb,
        const float* __restrict__ tW, const float* __restrict__ tb,
        const int* __restrict__ rowptr, const int* __restrict__ deg,
        float* __restrict__ H32, double* __restrict__ partials, int N) {
    __shared__ h2 wt2[64 * 32];        // 8 KB
    __shared__ float tbias[32];
    __shared__ h2 aLds2[4][66];
    __shared__ double sp1[4][32], sp2[4][32];
    int t = threadIdx.x;
    for (int i = t; i < 64 * 32; i += 256) {
        int dp = i >> 5, j = i & 31;
        wt2[i] = f2h2(tW[(size_t)(2 * dp) * 32 + j], tW[(size_t)(2 * dp + 1) * 32 + j]);
    }
    if (t < 32) tbias[t] = tb[t];
    __syncthreads();

    int wvid = t >> 6;
    int l64 = t & 63;
    int slot = l64 >> 5;
    int lane = l64 & 31;
    const float4 we4 = *(const float4*)&We[lane * 4];
    h2 weh0 = f2h2(we4.x, we4.y), weh1 = f2h2(we4.z, we4.w);
    const float4 wb0 = *(const float4*)&Wb[lane * 4];
    const float4 wb1 = *(const float4*)&Wb[128 + lane * 4];
    const float4 wb2 = *(const float4*)&Wb[256 + lane * 4];
    h2 zeroH; zeroH.x = (_Float16)0.f; zeroH.y = (_Float16)0.f;

    double s1 = 0.0, s2 = 0.0;   // slot-0 stat accumulators

    int waveGlobal = blockIdx.x * 4 + wvid;
    int totalWaves = gridDim.x * 4;
    for (int n = waveGlobal; n < N; n += totalWaves) {
        const h2* qp = (const h2*)(Q + (size_t)n * 128 + lane * 4);
        h2 qh0 = qp[0], qh1 = qp[1];
        float qwe = fdot2f(qh0, weh0, fdot2f(qh1, weh1, 0.f));
        qwe += __shfl_xor(qwe, 1); qwe += __shfl_xor(qwe, 2); qwe += __shfl_xor(qwe, 4);

        int start = rowptr[n];
        int d = deg[n];

        float m = -INFINITY, den = 0.f, plsum = 0.f;
        float nx = 0.f, ny = 0.f, nz = 0.f, nw = 0.f;

        int idx = slot;
        bool have = idx < d;
        float l0 = 0.f;
        h2 k0a = zeroH, k0b = zeroH, v0a = zeroH, v0b = zeroH;
        if (have) {
            int2 sl = srclat[start + idx];
            l0 = __int_as_float(sl.y);
            const h2* kp = (const h2*)(KV + (size_t)sl.x * 256 + lane * 4);
            const h2* vp = (const h2*)(KV + (size_t)sl.x * 256 + 128 + lane * 4);
            k0a = kp[0]; k0b = kp[1]; v0a = vp[0]; v0b = vp[1];
        }
        while (have) {
            int idx2 = idx + 2;
            bool have2 = idx2 < d;
            float l1 = 0.f;
            h2 k1a = zeroH, k1b = zeroH, v1a = zeroH, v1b = zeroH;
            if (have2) {   // issue next gathers BEFORE current math
                int2 sl = srclat[start + idx2];
                l1 = __int_as_float(sl.y);
                const h2* kp = (const h2*)(KV + (size_t)sl.x * 256 + lane * 4);
                const h2* vp = (const h2*)(KV + (size_t)sl.x * 256 + 128 + lane * 4);
                k1a = kp[0]; k1b = kp[1]; v1a = vp[0]; v1b = vp[1];
            }

            float t0 = fdot2f(qh0, k0a, fdot2f(qh1, k0b, 0.f));
            t0 += __shfl_xor(t0, 1); t0 += __shfl_xor(t0, 2); t0 += __shfl_xor(t0, 4);
            float alpha = fmaf(l0, qwe, t0) * 0.17677669529663687f;

            float mn = fmaxf(m, alpha);
            float sc = __expf(m - mn);
            float p = __expf(alpha - mn);
            nx = nx * sc + p * (float)v0a.x;
            ny = ny * sc + p * (float)v0a.y;
            nz = nz * sc + p * (float)v0b.x;
            nw = nw * sc + p * (float)v0b.y;
            plsum = plsum * sc + p * l0;
            den = den * sc + p;
            m = mn;

            idx = idx2; l0 = l1;
            k0a = k1a; k0b = k1b; v0a = v1a; v0b = v1b;
            have = have2;
        }

        float mo = __shfl_xor(m, 32);
        float mf = fmaxf(m, mo);
        float myscale = (m == -INFINITY) ? 0.f : __expf(m - mf);
        nx *= myscale; ny *= myscale; nz *= myscale; nw *= myscale;
        den *= myscale; plsum *= myscale;
        nx += __shfl_xor(nx, 32); ny += __shfl_xor(ny, 32);
        nz += __shfl_xor(nz, 32); nw += __shfl_xor(nw, 32);
        den += __shfl_xor(den, 32); plsum += __shfl_xor(plsum, 32);
        float inv = 1.f / (den + 1e-16f);
        float ox = fmaf(plsum, we4.x, nx) * inv;
        float oy = fmaf(plsum, we4.y, ny) * inv;
        float oz = fmaf(plsum, we4.z, nz) * inv;
        float ow = fmaf(plsum, we4.w, nw) * inv;

        const __half2* rp = (const __half2*)(R + (size_t)n * 128 + lane * 4);
        float2 ra = __half22float2(rp[0]), rb = __half22float2(rp[1]);
        float g = ox * wb0.x + ra.x * wb1.x + (ox - ra.x) * wb2.x
                + oy * wb0.y + ra.y * wb1.y + (oy - ra.y) * wb2.y
                + oz * wb0.z + rb.x * wb1.z + (oz - rb.x) * wb2.z
                + ow * wb0.w + rb.y * wb1.w + (ow - rb.y) * wb2.w;
        g += __shfl_xor(g, 1); g += __shfl_xor(g, 2); g += __shfl_xor(g, 4);
        g += __shfl_xor(g, 8); g += __shfl_xor(g, 16);
        float beta = 1.0f / (1.0f + __expf(-g));

        if (slot == 0) {
            float a0 = beta * ra.x + (1.0f - beta) * ox;
            float a1 = beta * ra.y + (1.0f - beta) * oy;
            float a2 = beta * rb.x + (1.0f - beta) * oz;
            float a3 = beta * rb.y + (1.0f - beta) * ow;
            aLds2[wvid][lane * 2 + 0] = f2h2(a0, a1);
            aLds2[wvid][lane * 2 + 1] = f2h2(a2, a3);
        }
        __builtin_amdgcn_wave_barrier();   // ordering only; free

        // fused Y = relu(A @ tW + tb): 16 fdot2 per slot, combined via xor 32
        float acc = (slot == 0) ? tbias[lane] : 0.f;
        int dpb = slot * 32;
#pragma unroll 8
        for (int i = 0; i < 32; ++i) {
            int dp = dpb + i;
            acc = fdot2f(aLds2[wvid][dp], wt2[dp * 32 + lane], acc);
        }
        acc += __shfl_xor(acc, 32);
        float y = fmaxf(acc, 0.f);
        if (slot == 0) {
            H32[(size_t)n * 32 + lane] = y;
            s1 += (double)y; s2 += (double)y * y;
        }
        __builtin_amdgcn_wave_barrier();
    }

    if (slot == 0) { sp1[wvid][lane] = s1; sp2[wvid][lane] = s2; }
    __syncthreads();
    if (t < 32) {
        double a1 = sp1[0][t] + sp1[1][t] + sp1[2][t] + sp1[3][t];
        double a2 = sp2[0][t] + sp2[1][t] + sp2[2][t] + sp2[3][t];
        partials[(size_t)blockIdx.x * 64 + t] = a1;
        partials[(size_t)blockIdx.x * 64 + 32 + t] = a2;
    }
}

// ---------------------------------------------------------------------------
// Two-stage stat reduction (separate kernels — free inter-dispatch barrier).
// ---------------------------------------------------------------------------
__global__ void k_statred1(const double* __restrict__ partials,
                           double* __restrict__ partial2, int nblocks) {
    __shared__ double red[4][64];
    int t = threadIdx.x;
    int col = t & 63, chunk = t >> 6;
    double a = 0;
    for (int bidx = blockIdx.x * 4 + chunk; bidx < nblocks; bidx += SRBLK * 4)
        a += partials[(size_t)bidx * 64 + col];
    red[chunk][col] = a;
    __syncthreads();
    if (t < 64)
        partial2[(size_t)blockIdx.x * 64 + t] =
            red[0][t] + red[1][t] + red[2][t] + red[3][t];
}

__global__ void k_statred2(const double* __restrict__ partial2,
                           double* __restrict__ SUM, double* __restrict__ SUMSQ) {
    __shared__ double red[4][64];
    int t = threadIdx.x;
    int col = t & 63, chunk = t >> 6;
    double a = 0;
    for (int bidx = chunk; bidx < SRBLK; bidx += 4)
        a += partial2[(size_t)bidx * 64 + col];
    red[chunk][col] = a;
    __syncthreads();
    if (t < 64) {
        double s = red[0][t] + red[1][t] + red[2][t] + red[3][t];
        if (t < 32) SUM[t] = s; else SUMSQ[t - 32] = s;
    }
}

// ---------------------------------------------------------------------------
// k_mlp1: BN affine + 32->128 relu. Block 0 zero-inits head scratch.
// ---------------------------------------------------------------------------
__global__ __launch_bounds__(256) void k_mlp1(
        const float* __restrict__ H32,
        const double* __restrict__ SUM, const double* __restrict__ SUMSQ,
        const float* __restrict__ bng, const float* __restrict__ bnb,
        const float* __restrict__ W1, const float* __restrict__ b1,
        float* __restrict__ Y1, unsigned int* __restrict__ smallbuf, int N) {
    __shared__ float w1[32 * 128];
    __shared__ float sb1[128];
    __shared__ float sscale[32], sshift[32];
    __shared__ float xs[32][36];
    int t = threadIdx.x;
    if (blockIdx.x == 0 && t < 16) smallbuf[t] = 0u;  // zero 64 B head scratch
    for (int i = t; i < 32 * 128; i += 256) w1[i] = W1[i];
    if (t < 128) sb1[t] = b1[t];
    if (t < 32) {
        double m = SUM[t] / N;
        double v = SUMSQ[t] / N - m * m;
        float inv = rsqrtf((float)v + 1e-5f);
        float sc = inv * bng[t];
        sscale[t] = sc;
        sshift[t] = bnb[t] - (float)m * sc;
    }
    int quad = t & 31, sub = t >> 5;
    int tiles = (N + 31) >> 5;
    for (int tile = blockIdx.x; tile < tiles; tile += gridDim.x) {
        int base = tile << 5;
        __syncthreads();
        {
            int nl = t >> 3, q = t & 7;
            int n = base + nl;
            float4 xv = make_float4(0.f, 0.f, 0.f, 0.f);
            if (n < N) xv = *(const float4*)&H32[(size_t)n * 32 + q * 4];
            xs[nl][q * 4 + 0] = xv.x * sscale[q * 4 + 0] + sshift[q * 4 + 0];
            xs[nl][q * 4 + 1] = xv.y * sscale[q * 4 + 1] + sshift[q * 4 + 1];
            xs[nl][q * 4 + 2] = xv.z * sscale[q * 4 + 2] + sshift[q * 4 + 2];
            xs[nl][q * 4 + 3] = xv.w * sscale[q * 4 + 3] + sshift[q * 4 + 3];
        }
        __syncthreads();
        float a[4][4];
#pragma unroll
        for (int k = 0; k < 4; ++k)
#pragma unroll
            for (int c = 0; c < 4; ++c) a[k][c] = sb1[quad * 4 + c];
        for (int d = 0; d < 32; ++d) {
            float4 w4 = *(const float4*)&w1[d * 128 + quad * 4];
#pragma unroll
            for (int k = 0; k < 4; ++k) {
                float x = xs[sub * 4 + k][d];
                a[k][0] = fmaf(x, w4.x, a[k][0]);
                a[k][1] = fmaf(x, w4.y, a[k][1]);
                a[k][2] = fmaf(x, w4.z, a[k][2]);
                a[k][3] = fmaf(x, w4.w, a[k][3]);
            }
        }
#pragma unroll
        for (int k = 0; k < 4; ++k) {
            int n = base + sub * 4 + k;
            if (n < N) {
                float4 yv;
                yv.x = fmaxf(a[k][0], 0.f); yv.y = fmaxf(a[k][1], 0.f);
                yv.z = fmaxf(a[k][2], 0.f); yv.w = fmaxf(a[k][3], 0.f);
                *(float4*)&Y1[(size_t)n * 128 + quad * 4] = yv;
            }
        }
    }
}

// ---------------------------------------------------------------------------
// k_mlp2: 128->64 relu.
// ---------------------------------------------------------------------------
__global__ __launch_bounds__(256) void k_mlp2(
        const float* __restrict__ Y1, const float* __restrict__ W2,
        const float* __restrict__ b2, float* __restrict__ Y2, int N) {
    __shared__ float w2f[128 * 64];
    __shared__ float sb2[64];
    __shared__ float xs[32][132];
    int t = threadIdx.x;
    for (int i = t; i < 128 * 64; i += 256) w2f[i] = W2[i];
    if (t < 64) sb2[t] = b2[t];
    int quad = t & 15, sub = t >> 4;
    int tiles = (N + 31) >> 5;
    for (int tile = blockIdx.x; tile < tiles; tile += gridDim.x) {
        int base = tile << 5;
        __syncthreads();
#pragma unroll
        for (int k = 0; k < 4; ++k) {
            int i = t + 256 * k;
            int nl = i >> 5, q = i & 31;
            int n = base + nl;
            float4 xv = make_float4(0.f, 0.f, 0.f, 0.f);
            if (n < N) xv = *(const float4*)&Y1[(size_t)n * 128 + q * 4];
            *(float4*)&xs[nl][q * 4] = xv;
        }
        __syncthreads();
        float a[2][4];
#pragma unroll
        for (int k = 0; k < 2; ++k)
#pragma unroll
            for (int c = 0; c < 4; ++c) a[k][c] = sb2[quad * 4 + c];
        for (int d = 0; d < 128; ++d) {
            float4 w4 = *(const float4*)&w2f[d * 64 + quad * 4];
#pragma unroll
            for (int k = 0; k < 2; ++k) {
                float x = xs[sub * 2 + k][d];
                a[k][0] = fmaf(x, w4.x, a[k][0]);
                a[k][1] = fmaf(x, w4.y, a[k][1]);
                a[k][2] = fmaf(x, w4.z, a[k][2]);
                a[k][3] = fmaf(x, w4.w, a[k][3]);
            }
        }
#pragma unroll
        for (int k = 0; k < 2; ++k) {
            int n = base + sub * 2 + k;
            if (n < N) {
                float4 yv;
                yv.x = fmaxf(a[k][0], 0.f); yv.y = fmaxf(a[k][1], 0.f);
                yv.z = fmaxf(a[k][2], 0.f); yv.w = fmaxf(a[k][3], 0.f);
                *(float4*)&Y2[(size_t)n * 64 + quad * 4] = yv;
            }
        }
    }
}

// ---------------------------------------------------------------------------
// k_mlp3: 64->64 (no relu), pure GEMV.
// ---------------------------------------------------------------------------
__global__ __launch_bounds__(256) void k_mlp3(
        const float* __restrict__ Y2, const float* __restrict__ W3,
        const float* __restrict__ b3, float* __restrict__ X3, int N) {
    __shared__ float w3[64 * 64];
    __shared__ float sb3[64];
    __shared__ float xs[32][68];
    int t = threadIdx.x;
    for (int i = t; i < 64 * 64; i += 256) w3[i] = W3[i];
    if (t < 64) sb3[t] = b3[t];
    int quad = t & 15, sub = t >> 4;
    int tiles = (N + 31) >> 5;
    for (int tile = blockIdx.x; tile < tiles; tile += gridDim.x) {
        int base = tile << 5;
        __syncthreads();
#pragma unroll
        for (int k = 0; k < 2; ++k) {
            int i = t + 256 * k;
            int nl = i >> 4, q = i & 15;
            int n = base + nl;
            float4 xv = make_float4(0.f, 0.f, 0.f, 0.f);
            if (n < N) xv = *(const float4*)&Y2[(size_t)n * 64 + q * 4];
            *(float4*)&xs[nl][q * 4] = xv;
        }
        __syncthreads();
        float a[2][4];
#pragma unroll
        for (int k = 0; k < 2; ++k)
#pragma unroll
            for (int c = 0; c < 4; ++c) a[k][c] = sb3[quad * 4 + c];
        for (int d = 0; d < 64; ++d) {
            float4 w4 = *(const float4*)&w3[d * 64 + quad * 4];
#pragma unroll
            for (int k = 0; k < 2; ++k) {
                float x = xs[sub * 2 + k][d];
                a[k][0] = fmaf(x, w4.x, a[k][0]);
                a[k][1] = fmaf(x, w4.y, a[k][1]);
                a[k][2] = fmaf(x, w4.z, a[k][2]);
                a[k][3] = fmaf(x, w4.w, a[k][3]);
            }
        }
#pragma unroll
        for (int k = 0; k < 2; ++k) {
            int n = base + sub * 2 + k;
            if (n < N)
                *(float4*)&X3[(size_t)n * 64 + quad * 4] = *(float4*)a[k];
        }
    }
}

// ---------------------------------------------------------------------------
// Head kernels
// ---------------------------------------------------------------------------
__global__ void k_head1(const float* __restrict__ X3, const float* __restrict__ remW,
                        const float* __restrict__ remB, const int* __restrict__ active,
                        float* __restrict__ l1out, unsigned long long* __restrict__ slot1,
                        unsigned int* __restrict__ m1, int N) {
    int n = blockIdx.x * 256 + threadIdx.x;
    if (n >= N) return;
    const float* xr = X3 + (size_t)n * 64;
    float acc = remB[0];
    for (int d = 0; d < 64; d++) acc = fmaf(xr[d], remW[d], acc);
    float maskf = (active[n] == 1) ? 0.f : NEGF;
    float rm = (n < 15) ? ((maskf == 0.f) ? NEGF : 0.f) : maskf;
    float l1 = acc + rm;
    l1out[n] = l1;
    atomicMax(m1, fmono(l1));
    float z = l1 + gumbel_at(n, 0, N);
    unsigned long long p = ((unsigned long long)fmono(z) << 32) |
                           (unsigned long long)(0xFFFFFFFFu - (unsigned)n);
    atomicMax(slot1, p);
}

__global__ void k_head2(const float* __restrict__ X3, const float* __restrict__ addW,
                        const float* __restrict__ addB,
                        const unsigned long long* __restrict__ slot1,
                        float* __restrict__ tvec, int* __restrict__ a1buf) {
    int j = threadIdx.x;  // 64
    unsigned long long p = *slot1;
    int a1 = (int)(0xFFFFFFFFu - (unsigned)(p & 0xFFFFFFFFull));
    const float* xr = X3 + (size_t)a1 * 64;
    float acc = addB[j];
    for (int d = 0; d < 64; d++) acc = fmaf(xr[d], addW[d * 64 + j], acc);
    tvec[j] = tanhf(acc);
    if (j == 0) *a1buf = a1;
}

__global__ void k_head3(const float* __restrict__ X3, const float* __restrict__ tvec,
                        const int* __restrict__ active, const int* __restrict__ a1buf,
                        float* __restrict__ l2out, unsigned long long* __restrict__ slot2,
                        unsigned int* __restrict__ m2, int N) {
    int n = blockIdx.x * 256 + threadIdx.x;
    if (n >= N) return;
    const float* xr = X3 + (size_t)n * 64;
    float acc = 0.f;
    for (int d = 0; d < 64; d++) acc = fmaf(xr[d], tvec[d], acc);
    float maskf = (active[n] == 1) ? 0.f : NEGF;
    if (n == *a1buf) maskf = 0.f;
    float l2 = acc + maskf;
    l2out[n] = l2;
    atomicMax(m2, fmono(l2));
    float z = l2 + gumbel_at(n, 1, N);
    unsigned long long p = ((unsigned long long)fmono(z) << 32) |
                           (unsigned long long)(0xFFFFFFFFu - (unsigned)n);
    atomicMax(slot2, p);
}

__global__ void k_sumexp(const float* __restrict__ l1, const float* __restrict__ l2,
                         const unsigned int* __restrict__ m1, const unsigned int* __restrict__ m2,
                         float* __restrict__ se, int N) {
    int t = blockIdx.x * 256 + threadIdx.x;
    float M1 = funmono(*m1), M2 = funmono(*m2);
    float e1 = 0.f, e2 = 0.f;
    if (t < N) { e1 = expf(l1[t] - M1); e2 = expf(l2[t] - M2); }
    __shared__ float r1[256], r2[256];
    r1[threadIdx.x] = e1; r2[threadIdx.x] = e2;
    __syncthreads();
    for (int s = 128; s > 0; s >>= 1) {
        if (threadIdx.x < s) { r1[threadIdx.x] += r1[threadIdx.x + s]; r2[threadIdx.x] += r2[threadIdx.x + s]; }
        __syncthreads();
    }
    if (threadIdx.x == 0) { atomicAdd(&se[0], r1[0]); atomicAdd(&se[1], r2[0]); }
}

__global__ void k_final(const float* __restrict__ l1, const float* __restrict__ l2,
                        const unsigned long long* __restrict__ slot2,
                        const int* __restrict__ a1buf,
                        const unsigned int* __restrict__ m1, const unsigned int* __restrict__ m2,
                        const float* __restrict__ se, float* __restrict__ outTail, int N) {
    int a1 = *a1buf;
    int a2 = (int)(0xFFFFFFFFu - (unsigned)((*slot2) & 0xFFFFFFFFull));
    outTail[0] = (float)a1;
    outTail[1] = (float)a2;
    outTail[2] = l1[a1] - (funmono(*m1) + logf(se[0]));
    outTail[3] = l2[a2] - (funmono(*m2) + logf(se[1]));
}

// ---------------------------------------------------------------------------
// Host launcher
// ---------------------------------------------------------------------------
extern "C" void kernel_launch(void* const* d_in, const int* in_sizes, int n_in,
                              void* d_out, int out_size, void* d_ws, size_t ws_size,
                              hipStream_t stream) {
    const float* node_type = (const float*)d_in[0];
    const float* requests  = (const float*)d_in[1];
    const float* latency   = (const float*)d_in[2];
    const int* edge_index  = (const int*)d_in[3];
    const int* active      = (const int*)d_in[4];
    int N = in_sizes[0];
    int E = in_sizes[2];
    const int* src = edge_index;
    const int* dst = edge_index + E;
    float* out = (float*)d_out;

    char* base = (char*)d_ws;
    size_t off = 0;
    auto alloc = [&](size_t bytes) -> char* {
        char* p = base + off;
        off += (bytes + 255) & ~(size_t)255;
        return p;
    };
    char* Abuf   = alloc((size_t)N * 128 * 4);  // fp32 Y2 (MLP stage)
    char* Qbuf   = alloc((size_t)N * 128 * 4);  // fp16 Q; later fp32 Y1
    __half* KV   = (__half*)alloc((size_t)N * 256 * 2); // interleaved K,V fp16
    char* Rbuf   = alloc((size_t)N * 128 * 4);  // fp16 R; later fp32 X3
    float* H32   = (float*)alloc((size_t)N * 32 * 4);
    int* deg     = (int*)alloc((size_t)N * 4);
    int* rowptr  = (int*)alloc((size_t)N * 4);
    int* cursor  = (int*)alloc((size_t)N * 4);
    int2* srclat = (int2*)alloc((size_t)E * 8);
    int* bsum    = (int*)alloc(1024 * 4);
    double* partials = (double*)alloc((size_t)ATTNGRID * 64 * 8);
    double* partial2 = (double*)alloc((size_t)SRBLK * 64 * 8);
    double* SUM  = (double*)alloc(512);
    double* SUMSQ = SUM + 32;
    char* small  = alloc(1024);
    unsigned long long* slot1 = (unsigned long long*)small;
    unsigned long long* slot2 = slot1 + 1;
    unsigned int* m1 = (unsigned int*)(small + 16);
    unsigned int* m2 = m1 + 1;
    float* se = (float*)(small + 24);
    int* a1buf = (int*)(small + 32);
    float* tvec = (float*)(small + 64);

    __half* Qh = (__half*)Qbuf;   float* Y1f = (float*)Qbuf;
    __half* Rh = (__half*)Rbuf;   float* X3f = (float*)Rbuf;
    float* Y2f = (float*)Abuf;

    int ng = (N + 255) / 256;
    int egE = (E + 255) / 256;
    int nb = ng;

    // ---- CSR build ----
    (void)hipMemsetAsync(deg, 0, (size_t)N * 4, stream);
    k_hist<<<egE, 256, 0, stream>>>(dst, deg, E);
    k_scan1<<<nb, 256, 0, stream>>>(deg, bsum, N);
    k_scan2<<<1, 256, 0, stream>>>(bsum, nb);
    k_scan3<<<nb, 256, 0, stream>>>(deg, bsum, rowptr, cursor, N);
    k_fill<<<egE, 256, 0, stream>>>(dst, src, latency, cursor, srclat, E);

    for (int L = 0; L < 5; ++L) {
        int din = L ? 32 : 2;
        const float* xin = L ? H32 : nullptr;
        const float* Wq = L ? (const float*)d_in[19] + (size_t)(L - 1) * 4096 : (const float*)d_in[5];
        const float* bq = L ? (const float*)d_in[20] + (size_t)(L - 1) * 128  : (const float*)d_in[6];
        const float* Wk = L ? (const float*)d_in[21] + (size_t)(L - 1) * 4096 : (const float*)d_in[7];
        const float* bk = L ? (const float*)d_in[22] + (size_t)(L - 1) * 128  : (const float*)d_in[8];
        const float* Wv = L ? (const float*)d_in[23] + (size_t)(L - 1) * 4096 : (const float*)d_in[9];
        const float* bv = L ? (const float*)d_in[24] + (size_t)(L - 1) * 128  : (const float*)d_in[10];
        const float* We = L ? (const float*)d_in[25] + (size_t)(L - 1) * 128  : (const float*)d_in[11];
        const float* Ws = L ? (const float*)d_in[26] + (size_t)(L - 1) * 4096 : (const float*)d_in[12];
        const float* bs = L ? (const float*)d_in[27] + (size_t)(L - 1) * 128  : (const float*)d_in[13];
        const float* Wb = L ? (const float*)d_in[28] + (size_t)(L - 1) * 384  : (const float*)d_in[14];
        const float* tW = L ? (const float*)d_in[29] + (size_t)(L - 1) * 4096 : (const float*)d_in[15];
        const float* tb = L ? (const float*)d_in[30] + (size_t)(L - 1) * 32   : (const float*)d_in[16];
        const float* bngP = (L == 1) ? (const float*)d_in[17]
                          : (L >= 2) ? (const float*)d_in[31] + (size_t)(L - 2) * 32 : nullptr;
        const float* bnbP = (L == 1) ? (const float*)d_in[18]
                          : (L >= 2) ? (const float*)d_in[32] + (size_t)(L - 2) * 32 : nullptr;

        k_qkvr<<<1024, 512, 0, stream>>>(xin, node_type, requests, din, N,
                                         Wq, bq, Wk, bk, Wv, bv, Ws, bs,
                                         SUM, SUMSQ, bngP, bnbP, (L > 0) ? 1 : 0,
                                         Qh, KV, Rh);
        k_attn<<<ATTNGRID, 256, 0, stream>>>(srclat, Qh, KV, We, Rh, Wb,
                                             tW, tb, rowptr, deg,
                                             H32, partials, N);
        k_statred1<<<SRBLK, 256, 0, stream>>>(partials, partial2, ATTNGRID);
        k_statred2<<<1, 256, 0, stream>>>(partial2, SUM, SUMSQ);
    }

    // embedding MLP (split for occupancy): H32 -> Y1(Qbuf) -> Y2(Abuf) -> X3(Rbuf)
    k_mlp1<<<512, 256, 0, stream>>>(H32, SUM, SUMSQ,
                                    (const float*)d_in[31] + 3 * 32,
                                    (const float*)d_in[32] + 3 * 32,
                                    (const float*)d_in[33], (const float*)d_in[34],
                                    Y1f, (unsigned int*)small, N);
    k_mlp2<<<512, 256, 0, stream>>>(Y1f, (const float*)d_in[35], (const float*)d_in[36],
                                    Y2f, N);
    k_mlp3<<<512, 256, 0, stream>>>(Y2f, (const float*)d_in[37], (const float*)d_in[38],
                                    X3f, N);
    // head
    k_head1<<<ng, 256, 0, stream>>>(X3f, (const float*)d_in[39], (const float*)d_in[40],
                                    active, out, slot1, m1, N);
    k_head2<<<1, 64, 0, stream>>>(X3f, (const float*)d_in[41], (const float*)d_in[42],
                                  slot1, tvec, a1buf);
    k_head3<<<ng, 256, 0, stream>>>(X3f, tvec, active, a1buf, out + N, slot2, m2, N);
    k_sumexp<<<ng, 256, 0, stream>>>(out, out + N, m1, m2, se, N);
    k_final<<<1, 1, 0, stream>>>(out, out + N, slot2, a1buf, m1, m2, se, out + 2 * N, N);
}

// Round 22
// 798.270 us; speedup vs baseline: 2.7539x; 1.0590x over previous
//
#include <hip/hip_runtime.h>
#include <hip/hip_fp16.h>
#include <cstdint>
#include <math.h>

typedef _Float16 h2 __attribute__((ext_vector_type(2)));

__device__ __forceinline__ h2 f2h2(float a, float b) {
    h2 r; r.x = (_Float16)a; r.y = (_Float16)b; return r;
}
__device__ __forceinline__ float fdot2f(h2 a, h2 b, float c) {
    return __builtin_amdgcn_fdot2(a, b, c, false);
}

// ---------------------------------------------------------------------------
// Threefry-2x32-20, exactly as JAX lowers it.
// ---------------------------------------------------------------------------
__device__ __forceinline__ uint32_t rotl32(uint32_t x, uint32_t n) {
    return (x << n) | (x >> (32u - n));
}

__device__ __forceinline__ void tf2x32(uint32_t k0, uint32_t k1,
                                       uint32_t x0, uint32_t x1,
                                       uint32_t& o0, uint32_t& o1) {
    uint32_t k2 = k0 ^ k1 ^ 0x1BD11BDAu;
    x0 += k0; x1 += k1;
    x0 += x1; x1 = rotl32(x1, 13); x1 ^= x0;
    x0 += x1; x1 = rotl32(x1, 15); x1 ^= x0;
    x0 += x1; x1 = rotl32(x1, 26); x1 ^= x0;
    x0 += x1; x1 = rotl32(x1, 6);  x1 ^= x0;
    x0 += k1; x1 += k2 + 1u;
    x0 += x1; x1 = rotl32(x1, 17); x1 ^= x0;
    x0 += x1; x1 = rotl32(x1, 29); x1 ^= x0;
    x0 += x1; x1 = rotl32(x1, 16); x1 ^= x0;
    x0 += x1; x1 = rotl32(x1, 24); x1 ^= x0;
    x0 += k2; x1 += k0 + 2u;
    x0 += x1; x1 = rotl32(x1, 13); x1 ^= x0;
    x0 += x1; x1 = rotl32(x1, 15); x1 ^= x0;
    x0 += x1; x1 = rotl32(x1, 26); x1 ^= x0;
    x0 += x1; x1 = rotl32(x1, 6);  x1 ^= x0;
    x0 += k0; x1 += k1 + 3u;
    x0 += x1; x1 = rotl32(x1, 17); x1 ^= x0;
    x0 += x1; x1 = rotl32(x1, 29); x1 ^= x0;
    x0 += x1; x1 = rotl32(x1, 16); x1 ^= x0;
    x0 += x1; x1 = rotl32(x1, 24); x1 ^= x0;
    x0 += k1; x1 += k2 + 4u;
    x0 += x1; x1 = rotl32(x1, 13); x1 ^= x0;
    x0 += x1; x1 = rotl32(x1, 15); x1 ^= x0;
    x0 += x1; x1 = rotl32(x1, 26); x1 ^= x0;
    x0 += x1; x1 = rotl32(x1, 6);  x1 ^= x0;
    x0 += k2; x1 += k0 + 5u;
    o0 = x0; o1 = x1;
}

__device__ float gumbel_at(int n, int which, int N) {
    uint32_t a0, a1, b0, b1;
    tf2x32(0u, 42u, 0u, 2u, a0, a1);   // constant-folded by compiler
    tf2x32(0u, 42u, 1u, 3u, b0, b1);
    uint32_t gk0 = which ? a1 : a0;
    uint32_t gk1 = which ? b1 : b0;
    int half = N >> 1;
    uint32_t o0, o1, bits;
    if (n < half) { tf2x32(gk0, gk1, (uint32_t)n, (uint32_t)(n + half), o0, o1); bits = o0; }
    else          { tf2x32(gk0, gk1, (uint32_t)(n - half), (uint32_t)n, o0, o1); bits = o1; }
    float f = __uint_as_float((bits >> 9) | 0x3F800000u) - 1.0f;
    float u = fmaxf(1.17549435e-38f, f);
    return -logf(-logf(u));
}

__device__ __forceinline__ uint32_t fmono(float f) {
    uint32_t b = __float_as_uint(f);
    return (b & 0x80000000u) ? ~b : (b | 0x80000000u);
}
__device__ __forceinline__ float funmono(uint32_t u) {
    uint32_t b = (u & 0x80000000u) ? (u & 0x7FFFFFFFu) : ~u;
    return __uint_as_float(b);
}

#define NEGF (-1e9f)
#define ATTNGRID 2048  /* persistent attn blocks */

// ---------------------------------------------------------------------------
// CSR build
// ---------------------------------------------------------------------------
__global__ void k_hist(const int* __restrict__ dstp, int* __restrict__ deg, int E) {
    int e = blockIdx.x * 256 + threadIdx.x;
    if (e < E) atomicAdd(&deg[dstp[e]], 1);
}

__global__ void k_scan1(const int* __restrict__ deg, int* __restrict__ bsum, int N) {
    __shared__ int s[256];
    int i = blockIdx.x * 256 + threadIdx.x;
    s[threadIdx.x] = (i < N) ? deg[i] : 0;
    __syncthreads();
    for (int st = 128; st > 0; st >>= 1) {
        if (threadIdx.x < st) s[threadIdx.x] += s[threadIdx.x + st];
        __syncthreads();
    }
    if (threadIdx.x == 0) bsum[blockIdx.x] = s[0];
}

__global__ void k_scan2(int* __restrict__ bsum, int nb) {
    __shared__ int s[256];
    int i = threadIdx.x;
    int v = (i < nb) ? bsum[i] : 0;
    s[i] = v;
    __syncthreads();
    for (int st = 1; st < 256; st <<= 1) {
        int t = (i >= st) ? s[i - st] : 0;
        __syncthreads();
        s[i] += t;
        __syncthreads();
    }
    if (i < nb) bsum[i] = s[i] - v;  // exclusive
}

__global__ void k_scan3(const int* __restrict__ deg, const int* __restrict__ bsum,
                        int* __restrict__ rowptr, int* __restrict__ cursor, int N) {
    __shared__ int s[256];
    int i = blockIdx.x * 256 + threadIdx.x;
    int v = (i < N) ? deg[i] : 0;
    s[threadIdx.x] = v;
    __syncthreads();
    for (int st = 1; st < 256; st <<= 1) {
        int t = (threadIdx.x >= st) ? s[threadIdx.x - st] : 0;
        __syncthreads();
        s[threadIdx.x] += t;
        __syncthreads();
    }
    int excl = s[threadIdx.x] - v + bsum[blockIdx.x];
    if (i < N) { rowptr[i] = excl; cursor[i] = excl; }
}

__global__ void k_fill(const int* __restrict__ dstp, const int* __restrict__ srcp,
                       const float* __restrict__ lat, int* __restrict__ cursor,
                       int2* __restrict__ srclat, int E) {
    int e = blockIdx.x * 256 + threadIdx.x;
    if (e < E) {
        int pos = atomicAdd(&cursor[dstp[e]], 1);
        srclat[pos] = make_int2(srcp[e], __float_as_int(lat[e]));
    }
}

// ---------------------------------------------------------------------------
// k_qkvr: batched GEMV via fp16 dot2 (fp32 accum). Weights in LDS as half2
// d-pairs (~37 KB -> 4 blocks/CU; grid 1024 exposes it). BN fused into
// x-staging. Outputs FP16: Q (128h), interleaved KV (256h), R (128h).
// ---------------------------------------------------------------------------
__global__ __launch_bounds__(512, 4) void k_qkvr(
        const float* __restrict__ xin, const float* __restrict__ nt,
        const float* __restrict__ rq, int din, int N,
        const float* __restrict__ Wq, const float* __restrict__ bq,
        const float* __restrict__ Wk, const float* __restrict__ bk,
        const float* __restrict__ Wv, const float* __restrict__ bv,
        const float* __restrict__ Ws, const float* __restrict__ bs,
        const double* __restrict__ SUM, const double* __restrict__ SUMSQ,
        const float* __restrict__ bng, const float* __restrict__ bnb,
        int applyBN,
        __half* __restrict__ Q, __half* __restrict__ KV, __half* __restrict__ R) {
    __shared__ h2 w2[4][16 * 128];     // 32 KB max
    __shared__ float bias[4][128];
    __shared__ h2 xs2[32][17];
    __shared__ float sscale[32], sshift[32];
    int t = threadIdx.x;
    int dpCount = din >> 1;            // 16 or 1
    for (int i = t; i < dpCount * 128; i += 512) {
        int dp = i >> 7, j = i & 127;
        w2[0][i] = f2h2(Wq[(size_t)(2 * dp) * 128 + j], Wq[(size_t)(2 * dp + 1) * 128 + j]);
        w2[1][i] = f2h2(Wk[(size_t)(2 * dp) * 128 + j], Wk[(size_t)(2 * dp + 1) * 128 + j]);
        w2[2][i] = f2h2(Wv[(size_t)(2 * dp) * 128 + j], Wv[(size_t)(2 * dp + 1) * 128 + j]);
        w2[3][i] = f2h2(Ws[(size_t)(2 * dp) * 128 + j], Ws[(size_t)(2 * dp + 1) * 128 + j]);
    }
    if (t < 128) {
        bias[0][t] = bq[t]; bias[1][t] = bk[t]; bias[2][t] = bv[t]; bias[3][t] = bs[t];
    }
    if (t < 32) {
        if (applyBN) {
            double m = SUM[t] / N;
            double v = SUMSQ[t] / N - m * m;
            float inv = rsqrtf((float)v + 1e-5f);
            float sc = inv * bng[t];
            sscale[t] = sc;
            sshift[t] = bnb[t] - (float)m * sc;
        } else {
            sscale[t] = 1.f; sshift[t] = 0.f;
        }
    }
    int quad = t & 31;
    int sub = t >> 5;   // 0..15, two nodes each
    int dpsh = (din == 32) ? 4 : 0;
    int tiles = (N + 31) >> 5;
    for (int tile = blockIdx.x; tile < tiles; tile += gridDim.x) {
        int base = tile << 5;
        __syncthreads();
        for (int i = t; i < 32 * dpCount; i += 512) {
            int nl = i >> dpsh, dp = i & (dpCount - 1);
            int nn = base + nl;
            float x0 = 0.f, x1 = 0.f;
            if (nn < N) {
                if (din == 2) { x0 = nt[nn]; x1 = rq[nn]; }
                else {
                    x0 = xin[(size_t)nn * din + 2 * dp];
                    x1 = xin[(size_t)nn * din + 2 * dp + 1];
                }
            }
            x0 = x0 * sscale[2 * dp] + sshift[2 * dp];
            x1 = x1 * sscale[2 * dp + 1] + sshift[2 * dp + 1];
            xs2[nl][dp] = f2h2(x0, x1);
        }
        __syncthreads();
        float acc[4][2][4];  // [mat][node][comp]
#pragma unroll
        for (int m = 0; m < 4; ++m)
#pragma unroll
            for (int k = 0; k < 2; ++k)
#pragma unroll
                for (int c = 0; c < 4; ++c) acc[m][k][c] = bias[m][quad * 4 + c];
        for (int dp = 0; dp < dpCount; ++dp) {
            h2 xv0 = xs2[sub * 2 + 0][dp];
            h2 xv1 = xs2[sub * 2 + 1][dp];
#pragma unroll
            for (int m = 0; m < 4; ++m) {
                const h2* wp = &w2[m][dp * 128 + quad * 4];
                h2 wa = wp[0], wb = wp[1], wc = wp[2], wd = wp[3];
                acc[m][0][0] = fdot2f(xv0, wa, acc[m][0][0]);
                acc[m][0][1] = fdot2f(xv0, wb, acc[m][0][1]);
                acc[m][0][2] = fdot2f(xv0, wc, acc[m][0][2]);
                acc[m][0][3] = fdot2f(xv0, wd, acc[m][0][3]);
                acc[m][1][0] = fdot2f(xv1, wa, acc[m][1][0]);
                acc[m][1][1] = fdot2f(xv1, wb, acc[m][1][1]);
                acc[m][1][2] = fdot2f(xv1, wc, acc[m][1][2]);
                acc[m][1][3] = fdot2f(xv1, wd, acc[m][1][3]);
            }
        }
#pragma unroll
        for (int k = 0; k < 2; ++k) {
            int n = base + sub * 2 + k;
            if (n < N) {
                *(__half2*)&Q[(size_t)n * 128 + quad * 4 + 0] =
                    __floats2half2_rn(acc[0][k][0], acc[0][k][1]);
                *(__half2*)&Q[(size_t)n * 128 + quad * 4 + 2] =
                    __floats2half2_rn(acc[0][k][2], acc[0][k][3]);
                *(__half2*)&KV[(size_t)n * 256 + quad * 4 + 0] =
                    __floats2half2_rn(acc[1][k][0], acc[1][k][1]);
                *(__half2*)&KV[(size_t)n * 256 + quad * 4 + 2] =
                    __floats2half2_rn(acc[1][k][2], acc[1][k][3]);
                *(__half2*)&KV[(size_t)n * 256 + 128 + quad * 4 + 0] =
                    __floats2half2_rn(acc[2][k][0], acc[2][k][1]);
                *(__half2*)&KV[(size_t)n * 256 + 128 + quad * 4 + 2] =
                    __floats2half2_rn(acc[2][k][2], acc[2][k][3]);
                *(__half2*)&R[(size_t)n * 128 + quad * 4 + 0] =
                    __floats2half2_rn(acc[3][k][0], acc[3][k][1]);
                *(__half2*)&R[(size_t)n * 128 + quad * 4 + 2] =
                    __floats2half2_rn(acc[3][k][2], acc[3][k][3]);
            }
        }
    }
}

// ---------------------------------------------------------------------------
// k_attn: persistent, wave-independent striding, fp16 dot2, algebraic We
// folding, fused GEMV. CROSS-NODE PREFETCH: next node's Q row, R row,
// rowptr and deg are issued before the current node's edge loop, so their
// waitcnt is hidden behind a full node of work. No device-scope fences.
// ---------------------------------------------------------------------------
__global__ __launch_bounds__(256) void k_attn(
        const int2* __restrict__ srclat,
        const __half* __restrict__ Q, const __half* __restrict__ KV,
        const float* __restrict__ We,
        const __half* __restrict__ R, const float* __restrict__ Wb,
        const float* __restrict__ tW, const float* __restrict__ tb,
        const int* __restrict__ rowptr, const int* __restrict__ deg,
        float* __restrict__ H32, double* __restrict__ partials, int N) {
    __shared__ h2 wt2[64 * 32];        // 8 KB
    __shared__ float tbias[32];
    __shared__ h2 aLds2[4][66];
    __shared__ double sp1[4][32], sp2[4][32];
    int t = threadIdx.x;
    for (int i = t; i < 64 * 32; i += 256) {
        int dp = i >> 5, j = i & 31;
        wt2[i] = f2h2(tW[(size_t)(2 * dp) * 32 + j], tW[(size_t)(2 * dp + 1) * 32 + j]);
    }
    if (t < 32) tbias[t] = tb[t];
    __syncthreads();

    int wvid = t >> 6;
    int l64 = t & 63;
    int slot = l64 >> 5;
    int lane = l64 & 31;
    const float4 we4 = *(const float4*)&We[lane * 4];
    h2 weh0 = f2h2(we4.x, we4.y), weh1 = f2h2(we4.z, we4.w);
    const float4 wb0 = *(const float4*)&Wb[lane * 4];
    const float4 wb1 = *(const float4*)&Wb[128 + lane * 4];
    const float4 wb2 = *(const float4*)&Wb[256 + lane * 4];
    h2 zeroH; zeroH.x = (_Float16)0.f; zeroH.y = (_Float16)0.f;

    double s1 = 0.0, s2 = 0.0;   // slot-0 stat accumulators

    int waveGlobal = blockIdx.x * 4 + wvid;
    int totalWaves = gridDim.x * 4;

    // prefetch the first node's per-node data
    h2 pq0 = zeroH, pq1 = zeroH;
    __half2 pr0 = __floats2half2_rn(0.f, 0.f), pr1 = pr0;
    int pstart = 0, pd = 0;
    if (waveGlobal < N) {
        const h2* qp = (const h2*)(Q + (size_t)waveGlobal * 128 + lane * 4);
        pq0 = qp[0]; pq1 = qp[1];
        const __half2* rp = (const __half2*)(R + (size_t)waveGlobal * 128 + lane * 4);
        pr0 = rp[0]; pr1 = rp[1];
        pstart = rowptr[waveGlobal];
        pd = deg[waveGlobal];
    }

    for (int n = waveGlobal; n < N; n += totalWaves) {
        h2 qh0 = pq0, qh1 = pq1;
        __half2 r0h = pr0, r1h = pr1;
        int start = pstart, d = pd;

        // issue NEXT node's loads now; waits land after this node's work
        int nn = n + totalWaves;
        if (nn < N) {
            const h2* qp = (const h2*)(Q + (size_t)nn * 128 + lane * 4);
            pq0 = qp[0]; pq1 = qp[1];
            const __half2* rp = (const __half2*)(R + (size_t)nn * 128 + lane * 4);
            pr0 = rp[0]; pr1 = rp[1];
            pstart = rowptr[nn];
            pd = deg[nn];
        }

        float qwe = fdot2f(qh0, weh0, fdot2f(qh1, weh1, 0.f));
        qwe += __shfl_xor(qwe, 1); qwe += __shfl_xor(qwe, 2); qwe += __shfl_xor(qwe, 4);

        float m = -INFINITY, den = 0.f, plsum = 0.f;
        float nx = 0.f, ny = 0.f, nz = 0.f, nw = 0.f;

        int idx = slot;
        bool have = idx < d;
        float l0 = 0.f;
        h2 k0a = zeroH, k0b = zeroH, v0a = zeroH, v0b = zeroH;
        if (have) {
            int2 sl = srclat[start + idx];
            l0 = __int_as_float(sl.y);
            const h2* kp = (const h2*)(KV + (size_t)sl.x * 256 + lane * 4);
            const h2* vp = (const h2*)(KV + (size_t)sl.x * 256 + 128 + lane * 4);
            k0a = kp[0]; k0b = kp[1]; v0a = vp[0]; v0b = vp[1];
        }
        while (have) {
            int idx2 = idx + 2;
            bool have2 = idx2 < d;
            float l1 = 0.f;
            h2 k1a = zeroH, k1b = zeroH, v1a = zeroH, v1b = zeroH;
            if (have2) {   // issue next gathers BEFORE current math
                int2 sl = srclat[start + idx2];
                l1 = __int_as_float(sl.y);
                const h2* kp = (const h2*)(KV + (size_t)sl.x * 256 + lane * 4);
                const h2* vp = (const h2*)(KV + (size_t)sl.x * 256 + 128 + lane * 4);
                k1a = kp[0]; k1b = kp[1]; v1a = vp[0]; v1b = vp[1];
            }

            float t0 = fdot2f(qh0, k0a, fdot2f(qh1, k0b, 0.f));
            t0 += __shfl_xor(t0, 1); t0 += __shfl_xor(t0, 2); t0 += __shfl_xor(t0, 4);
            float alpha = fmaf(l0, qwe, t0) * 0.17677669529663687f;

            float mn = fmaxf(m, alpha);
            float sc = __expf(m - mn);
            float p = __expf(alpha - mn);
            nx = nx * sc + p * (float)v0a.x;
            ny = ny * sc + p * (float)v0a.y;
            nz = nz * sc + p * (float)v0b.x;
            nw = nw * sc + p * (float)v0b.y;
            plsum = plsum * sc + p * l0;
            den = den * sc + p;
            m = mn;

            idx = idx2; l0 = l1;
            k0a = k1a; k0b = k1b; v0a = v1a; v0b = v1b;
            have = have2;
        }

        float mo = __shfl_xor(m, 32);
        float mf = fmaxf(m, mo);
        float myscale = (m == -INFINITY) ? 0.f : __expf(m - mf);
        nx *= myscale; ny *= myscale; nz *= myscale; nw *= myscale;
        den *= myscale; plsum *= myscale;
        nx += __shfl_xor(nx, 32); ny += __shfl_xor(ny, 32);
        nz += __shfl_xor(nz, 32); nw += __shfl_xor(nw, 32);
        den += __shfl_xor(den, 32); plsum += __shfl_xor(plsum, 32);
        float inv = 1.f / (den + 1e-16f);
        float ox = fmaf(plsum, we4.x, nx) * inv;
        float oy = fmaf(plsum, we4.y, ny) * inv;
        float oz = fmaf(plsum, we4.z, nz) * inv;
        float ow = fmaf(plsum, we4.w, nw) * inv;

        float2 ra = __half22float2(r0h), rb = __half22float2(r1h);
        float g = ox * wb0.x + ra.x * wb1.x + (ox - ra.x) * wb2.x
                + oy * wb0.y + ra.y * wb1.y + (oy - ra.y) * wb2.y
                + oz * wb0.z + rb.x * wb1.z + (oz - rb.x) * wb2.z
                + ow * wb0.w + rb.y * wb1.w + (ow - rb.y) * wb2.w;
        g += __shfl_xor(g, 1); g += __shfl_xor(g, 2); g += __shfl_xor(g, 4);
        g += __shfl_xor(g, 8); g += __shfl_xor(g, 16);
        float beta = 1.0f / (1.0f + __expf(-g));

        if (slot == 0) {
            float a0 = beta * ra.x + (1.0f - beta) * ox;
            float a1 = beta * ra.y + (1.0f - beta) * oy;
            float a2 = beta * rb.x + (1.0f - beta) * oz;
            float a3 = beta * rb.y + (1.0f - beta) * ow;
            aLds2[wvid][lane * 2 + 0] = f2h2(a0, a1);
            aLds2[wvid][lane * 2 + 1] = f2h2(a2, a3);
        }
        __builtin_amdgcn_wave_barrier();   // ordering only; free

        // fused Y = relu(A @ tW + tb): 16 fdot2 per slot, combined via xor 32
        float acc = (slot == 0) ? tbias[lane] : 0.f;
        int dpb = slot * 32;
#pragma unroll 8
        for (int i = 0; i < 32; ++i) {
            int dp = dpb + i;
            acc = fdot2f(aLds2[wvid][dp], wt2[dp * 32 + lane], acc);
        }
        acc += __shfl_xor(acc, 32);
        float y = fmaxf(acc, 0.f);
        if (slot == 0) {
            H32[(size_t)n * 32 + lane] = y;
            s1 += (double)y; s2 += (double)y * y;
        }
        __builtin_amdgcn_wave_barrier();
    }

    if (slot == 0) { sp1[wvid][lane] = s1; sp2[wvid][lane] = s2; }
    __syncthreads();
    if (t < 32) {
        double a1 = sp1[0][t] + sp1[1][t] + sp1[2][t] + sp1[3][t];
        double a2 = sp2[0][t] + sp2[1][t] + sp2[2][t] + sp2[3][t];
        partials[(size_t)blockIdx.x * 64 + t] = a1;
        partials[(size_t)blockIdx.x * 64 + 32 + t] = a2;
    }
}

// ---------------------------------------------------------------------------
// Single-kernel stat reduction: block = one output column (64 blocks),
// 256 threads stride over ATTNGRID rows, block tree-reduce. No fences.
// ---------------------------------------------------------------------------
__global__ void k_statred(const double* __restrict__ partials,
                          double* __restrict__ SUM, double* __restrict__ SUMSQ,
                          int nblocks) {
    __shared__ double s[256];
    int col = blockIdx.x;   // 0..63
    double a = 0;
    for (int b = threadIdx.x; b < nblocks; b += 256)
        a += partials[(size_t)b * 64 + col];
    s[threadIdx.x] = a;
    __syncthreads();
    for (int st = 128; st > 0; st >>= 1) {
        if (threadIdx.x < st) s[threadIdx.x] += s[threadIdx.x + st];
        __syncthreads();
    }
    if (threadIdx.x == 0) {
        if (col < 32) SUM[col] = s[0];
        else SUMSQ[col - 32] = s[0];
    }
}

// ---------------------------------------------------------------------------
// k_mlp1: BN affine + 32->128 relu. Block 0 zero-inits head scratch.
// ---------------------------------------------------------------------------
__global__ __launch_bounds__(256) void k_mlp1(
        const float* __restrict__ H32,
        const double* __restrict__ SUM, const double* __restrict__ SUMSQ,
        const float* __restrict__ bng, const float* __restrict__ bnb,
        const float* __restrict__ W1, const float* __restrict__ b1,
        float* __restrict__ Y1, unsigned int* __restrict__ smallbuf, int N) {
    __shared__ float w1[32 * 128];
    __shared__ float sb1[128];
    __shared__ float sscale[32], sshift[32];
    __shared__ float xs[32][36];
    int t = threadIdx.x;
    if (blockIdx.x == 0 && t < 16) smallbuf[t] = 0u;  // zero 64 B head scratch
    for (int i = t; i < 32 * 128; i += 256) w1[i] = W1[i];
    if (t < 128) sb1[t] = b1[t];
    if (t < 32) {
        double m = SUM[t] / N;
        double v = SUMSQ[t] / N - m * m;
        float inv = rsqrtf((float)v + 1e-5f);
        float sc = inv * bng[t];
        sscale[t] = sc;
        sshift[t] = bnb[t] - (float)m * sc;
    }
    int quad = t & 31, sub = t >> 5;
    int tiles = (N + 31) >> 5;
    for (int tile = blockIdx.x; tile < tiles; tile += gridDim.x) {
        int base = tile << 5;
        __syncthreads();
        {
            int nl = t >> 3, q = t & 7;
            int n = base + nl;
            float4 xv = make_float4(0.f, 0.f, 0.f, 0.f);
            if (n < N) xv = *(const float4*)&H32[(size_t)n * 32 + q * 4];
            xs[nl][q * 4 + 0] = xv.x * sscale[q * 4 + 0] + sshift[q * 4 + 0];
            xs[nl][q * 4 + 1] = xv.y * sscale[q * 4 + 1] + sshift[q * 4 + 1];
            xs[nl][q * 4 + 2] = xv.z * sscale[q * 4 + 2] + sshift[q * 4 + 2];
            xs[nl][q * 4 + 3] = xv.w * sscale[q * 4 + 3] + sshift[q * 4 + 3];
        }
        __syncthreads();
        float a[4][4];
#pragma unroll
        for (int k = 0; k < 4; ++k)
#pragma unroll
            for (int c = 0; c < 4; ++c) a[k][c] = sb1[quad * 4 + c];
        for (int d = 0; d < 32; ++d) {
            float4 w4 = *(const float4*)&w1[d * 128 + quad * 4];
#pragma unroll
            for (int k = 0; k < 4; ++k) {
                float x = xs[sub * 4 + k][d];
                a[k][0] = fmaf(x, w4.x, a[k][0]);
                a[k][1] = fmaf(x, w4.y, a[k][1]);
                a[k][2] = fmaf(x, w4.z, a[k][2]);
                a[k][3] = fmaf(x, w4.w, a[k][3]);
            }
        }
#pragma unroll
        for (int k = 0; k < 4; ++k) {
            int n = base + sub * 4 + k;
            if (n < N) {
                float4 yv;
                yv.x = fmaxf(a[k][0], 0.f); yv.y = fmaxf(a[k][1], 0.f);
                yv.z = fmaxf(a[k][2], 0.f); yv.w = fmaxf(a[k][3], 0.f);
                *(float4*)&Y1[(size_t)n * 128 + quad * 4] = yv;
            }
        }
    }
}

// ---------------------------------------------------------------------------
// k_mlp2: 128->64 relu.
// ---------------------------------------------------------------------------
__global__ __launch_bounds__(256) void k_mlp2(
        const float* __restrict__ Y1, const float* __restrict__ W2,
        const float* __restrict__ b2, float* __restrict__ Y2, int N) {
    __shared__ float w2f[128 * 64];
    __shared__ float sb2[64];
    __shared__ float xs[32][132];
    int t = threadIdx.x;
    for (int i = t; i < 128 * 64; i += 256) w2f[i] = W2[i];
    if (t < 64) sb2[t] = b2[t];
    int quad = t & 15, sub = t >> 4;
    int tiles = (N + 31) >> 5;
    for (int tile = blockIdx.x; tile < tiles; tile += gridDim.x) {
        int base = tile << 5;
        __syncthreads();
#pragma unroll
        for (int k = 0; k < 4; ++k) {
            int i = t + 256 * k;
            int nl = i >> 5, q = i & 31;
            int n = base + nl;
            float4 xv = make_float4(0.f, 0.f, 0.f, 0.f);
            if (n < N) xv = *(const float4*)&Y1[(size_t)n * 128 + q * 4];
            *(float4*)&xs[nl][q * 4] = xv;
        }
        __syncthreads();
        float a[2][4];
#pragma unroll
        for (int k = 0; k < 2; ++k)
#pragma unroll
            for (int c = 0; c < 4; ++c) a[k][c] = sb2[quad * 4 + c];
        for (int d = 0; d < 128; ++d) {
            float4 w4 = *(const float4*)&w2f[d * 64 + quad * 4];
#pragma unroll
            for (int k = 0; k < 2; ++k) {
                float x = xs[sub * 2 + k][d];
                a[k][0] = fmaf(x, w4.x, a[k][0]);
                a[k][1] = fmaf(x, w4.y, a[k][1]);
                a[k][2] = fmaf(x, w4.z, a[k][2]);
                a[k][3] = fmaf(x, w4.w, a[k][3]);
            }
        }
#pragma unroll
        for (int k = 0; k < 2; ++k) {
            int n = base + sub * 2 + k;
            if (n < N) {
                float4 yv;
                yv.x = fmaxf(a[k][0], 0.f); yv.y = fmaxf(a[k][1], 0.f);
                yv.z = fmaxf(a[k][2], 0.f); yv.w = fmaxf(a[k][3], 0.f);
                *(float4*)&Y2[(size_t)n * 64 + quad * 4] = yv;
            }
        }
    }
}

// ---------------------------------------------------------------------------
// k_mlp3: 64->64 (no relu), pure GEMV.
// ---------------------------------------------------------------------------
__global__ __launch_bounds__(256) void k_mlp3(
        const float* __restrict__ Y2, const float* __restrict__ W3,
        const float* __restrict__ b3, float* __restrict__ X3, int N) {
    __shared__ float w3[64 * 64];
    __shared__ float sb3[64];
    __shared__ float xs[32][68];
    int t = threadIdx.x;
    for (int i = t; i < 64 * 64; i += 256) w3[i] = W3[i];
    if (t < 64) sb3[t] = b3[t];
    int quad = t & 15, sub = t >> 4;
    int tiles = (N + 31) >> 5;
    for (int tile = blockIdx.x; tile < tiles; tile += gridDim.x) {
        int base = tile << 5;
        __syncthreads();
#pragma unroll
        for (int k = 0; k < 2; ++k) {
            int i = t + 256 * k;
            int nl = i >> 4, q = i & 15;
            int n = base + nl;
            float4 xv = make_float4(0.f, 0.f, 0.f, 0.f);
            if (n < N) xv = *(const float4*)&Y2[(size_t)n * 64 + q * 4];
            *(float4*)&xs[nl][q * 4] = xv;
        }
        __syncthreads();
        float a[2][4];
#pragma unroll
        for (int k = 0; k < 2; ++k)
#pragma unroll
            for (int c = 0; c < 4; ++c) a[k][c] = sb3[quad * 4 + c];
        for (int d = 0; d < 64; ++d) {
            float4 w4 = *(const float4*)&w3[d * 64 + quad * 4];
#pragma unroll
            for (int k = 0; k < 2; ++k) {
                float x = xs[sub * 2 + k][d];
                a[k][0] = fmaf(x, w4.x, a[k][0]);
                a[k][1] = fmaf(x, w4.y, a[k][1]);
                a[k][2] = fmaf(x, w4.z, a[k][2]);
                a[k][3] = fmaf(x, w4.w, a[k][3]);
            }
        }
#pragma unroll
        for (int k = 0; k < 2; ++k) {
            int n = base + sub * 2 + k;
            if (n < N)
                *(float4*)&X3[(size_t)n * 64 + quad * 4] = *(float4*)a[k];
        }
    }
}

// ---------------------------------------------------------------------------
// Head kernels
// ---------------------------------------------------------------------------
__global__ void k_head1(const float* __restrict__ X3, const float* __restrict__ remW,
                        const float* __restrict__ remB, const int* __restrict__ active,
                        float* __restrict__ l1out, unsigned long long* __restrict__ slot1,
                        unsigned int* __restrict__ m1, int N) {
    int n = blockIdx.x * 256 + threadIdx.x;
    if (n >= N) return;
    const float* xr = X3 + (size_t)n * 64;
    float acc = remB[0];
    for (int d = 0; d < 64; d++) acc = fmaf(xr[d], remW[d], acc);
    float maskf = (active[n] == 1) ? 0.f : NEGF;
    float rm = (n < 15) ? ((maskf == 0.f) ? NEGF : 0.f) : maskf;
    float l1 = acc + rm;
    l1out[n] = l1;
    atomicMax(m1, fmono(l1));
    float z = l1 + gumbel_at(n, 0, N);
    unsigned long long p = ((unsigned long long)fmono(z) << 32) |
                           (unsigned long long)(0xFFFFFFFFu - (unsigned)n);
    atomicMax(slot1, p);
}

__global__ void k_head2(const float* __restrict__ X3, const float* __restrict__ addW,
                        const float* __restrict__ addB,
                        const unsigned long long* __restrict__ slot1,
                        float* __restrict__ tvec, int* __restrict__ a1buf) {
    int j = threadIdx.x;  // 64
    unsigned long long p = *slot1;
    int a1 = (int)(0xFFFFFFFFu - (unsigned)(p & 0xFFFFFFFFull));
    const float* xr = X3 + (size_t)a1 * 64;
    float acc = addB[j];
    for (int d = 0; d < 64; d++) acc = fmaf(xr[d], addW[d * 64 + j], acc);
    tvec[j] = tanhf(acc);
    if (j == 0) *a1buf = a1;
}

__global__ void k_head3(const float* __restrict__ X3, const float* __restrict__ tvec,
                        const int* __restrict__ active, const int* __restrict__ a1buf,
                        float* __restrict__ l2out, unsigned long long* __restrict__ slot2,
                        unsigned int* __restrict__ m2, int N) {
    int n = blockIdx.x * 256 + threadIdx.x;
    if (n >= N) return;
    const float* xr = X3 + (size_t)n * 64;
    float acc = 0.f;
    for (int d = 0; d < 64; d++) acc = fmaf(xr[d], tvec[d], acc);
    float maskf = (active[n] == 1) ? 0.f : NEGF;
    if (n == *a1buf) maskf = 0.f;
    float l2 = acc + maskf;
    l2out[n] = l2;
    atomicMax(m2, fmono(l2));
    float z = l2 + gumbel_at(n, 1, N);
    unsigned long long p = ((unsigned long long)fmono(z) << 32) |
                           (unsigned long long)(0xFFFFFFFFu - (unsigned)n);
    atomicMax(slot2, p);
}

__global__ void k_sumexp(const float* __restrict__ l1, const float* __restrict__ l2,
                         const unsigned int* __restrict__ m1, const unsigned int* __restrict__ m2,
                         float* __restrict__ se, int N) {
    int t = blockIdx.x * 256 + threadIdx.x;
    float M1 = funmono(*m1), M2 = funmono(*m2);
    float e1 = 0.f, e2 = 0.f;
    if (t < N) { e1 = expf(l1[t] - M1); e2 = expf(l2[t] - M2); }
    __shared__ float r1[256], r2[256];
    r1[threadIdx.x] = e1; r2[threadIdx.x] = e2;
    __syncthreads();
    for (int s = 128; s > 0; s >>= 1) {
        if (threadIdx.x < s) { r1[threadIdx.x] += r1[threadIdx.x + s]; r2[threadIdx.x] += r2[threadIdx.x + s]; }
        __syncthreads();
    }
    if (threadIdx.x == 0) { atomicAdd(&se[0], r1[0]); atomicAdd(&se[1], r2[0]); }
}

__global__ void k_final(const float* __restrict__ l1, const float* __restrict__ l2,
                        const unsigned long long* __restrict__ slot2,
                        const int* __restrict__ a1buf,
                        const unsigned int* __restrict__ m1, const unsigned int* __restrict__ m2,
                        const float* __restrict__ se, float* __restrict__ outTail, int N) {
    int a1 = *a1buf;
    int a2 = (int)(0xFFFFFFFFu - (unsigned)((*slot2) & 0xFFFFFFFFull));
    outTail[0] = (float)a1;
    outTail[1] = (float)a2;
    outTail[2] = l1[a1] - (funmono(*m1) + logf(se[0]));
    outTail[3] = l2[a2] - (funmono(*m2) + logf(se[1]));
}

// ---------------------------------------------------------------------------
// Host launcher
// ---------------------------------------------------------------------------
extern "C" void kernel_launch(void* const* d_in, const int* in_sizes, int n_in,
                              void* d_out, int out_size, void* d_ws, size_t ws_size,
                              hipStream_t stream) {
    const float* node_type = (const float*)d_in[0];
    const float* requests  = (const float*)d_in[1];
    const float* latency   = (const float*)d_in[2];
    const int* edge_index  = (const int*)d_in[3];
    const int* active      = (const int*)d_in[4];
    int N = in_sizes[0];
    int E = in_sizes[2];
    const int* src = edge_index;
    const int* dst = edge_index + E;
    float* out = (float*)d_out;

    char* base = (char*)d_ws;
    size_t off = 0;
    auto alloc = [&](size_t bytes) -> char* {
        char* p = base + off;
        off += (bytes + 255) & ~(size_t)255;
        return p;
    };
    char* Abuf   = alloc((size_t)N * 128 * 4);  // fp32 Y2 (MLP stage)
    char* Qbuf   = alloc((size_t)N * 128 * 4);  // fp16 Q; later fp32 Y1
    __half* KV   = (__half*)alloc((size_t)N * 256 * 2); // interleaved K,V fp16
    char* Rbuf   = alloc((size_t)N * 128 * 4);  // fp16 R; later fp32 X3
    float* H32   = (float*)alloc((size_t)N * 32 * 4);
    int* deg     = (int*)alloc((size_t)N * 4);
    int* rowptr  = (int*)alloc((size_t)N * 4);
    int* cursor  = (int*)alloc((size_t)N * 4);
    int2* srclat = (int2*)alloc((size_t)E * 8);
    int* bsum    = (int*)alloc(1024 * 4);
    double* partials = (double*)alloc((size_t)ATTNGRID * 64 * 8);
    double* SUM  = (double*)alloc(512);
    double* SUMSQ = SUM + 32;
    char* small  = alloc(1024);
    unsigned long long* slot1 = (unsigned long long*)small;
    unsigned long long* slot2 = slot1 + 1;
    unsigned int* m1 = (unsigned int*)(small + 16);
    unsigned int* m2 = m1 + 1;
    float* se = (float*)(small + 24);
    int* a1buf = (int*)(small + 32);
    float* tvec = (float*)(small + 64);

    __half* Qh = (__half*)Qbuf;   float* Y1f = (float*)Qbuf;
    __half* Rh = (__half*)Rbuf;   float* X3f = (float*)Rbuf;
    float* Y2f = (float*)Abuf;

    int ng = (N + 255) / 256;
    int egE = (E + 255) / 256;
    int nb = ng;

    // ---- CSR build ----
    (void)hipMemsetAsync(deg, 0, (size_t)N * 4, stream);
    k_hist<<<egE, 256, 0, stream>>>(dst, deg, E);
    k_scan1<<<nb, 256, 0, stream>>>(deg, bsum, N);
    k_scan2<<<1, 256, 0, stream>>>(bsum, nb);
    k_scan3<<<nb, 256, 0, stream>>>(deg, bsum, rowptr, cursor, N);
    k_fill<<<egE, 256, 0, stream>>>(dst, src, latency, cursor, srclat, E);

    for (int L = 0; L < 5; ++L) {
        int din = L ? 32 : 2;
        const float* xin = L ? H32 : nullptr;
        const float* Wq = L ? (const float*)d_in[19] + (size_t)(L - 1) * 4096 : (const float*)d_in[5];
        const float* bq = L ? (const float*)d_in[20] + (size_t)(L - 1) * 128  : (const float*)d_in[6];
        const float* Wk = L ? (const float*)d_in[21] + (size_t)(L - 1) * 4096 : (const float*)d_in[7];
        const float* bk = L ? (const float*)d_in[22] + (size_t)(L - 1) * 128  : (const float*)d_in[8];
        const float* Wv = L ? (const float*)d_in[23] + (size_t)(L - 1) * 4096 : (const float*)d_in[9];
        const float* bv = L ? (const float*)d_in[24] + (size_t)(L - 1) * 128  : (const float*)d_in[10];
        const float* We = L ? (const float*)d_in[25] + (size_t)(L - 1) * 128  : (const float*)d_in[11];
        const float* Ws = L ? (const float*)d_in[26] + (size_t)(L - 1) * 4096 : (const float*)d_in[12];
        const float* bs = L ? (const float*)d_in[27] + (size_t)(L - 1) * 128  : (const float*)d_in[13];
        const float* Wb = L ? (const float*)d_in[28] + (size_t)(L - 1) * 384  : (const float*)d_in[14];
        const float* tW = L ? (const float*)d_in[29] + (size_t)(L - 1) * 4096 : (const float*)d_in[15];
        const float* tb = L ? (const float*)d_in[30] + (size_t)(L - 1) * 32   : (const float*)d_in[16];
        const float* bngP = (L == 1) ? (const float*)d_in[17]
                          : (L >= 2) ? (const float*)d_in[31] + (size_t)(L - 2) * 32 : nullptr;
        const float* bnbP = (L == 1) ? (const float*)d_in[18]
                          : (L >= 2) ? (const float*)d_in[32] + (size_t)(L - 2) * 32 : nullptr;

        k_qkvr<<<1024, 512, 0, stream>>>(xin, node_type, requests, din, N,
                                         Wq, bq, Wk, bk, Wv, bv, Ws, bs,
                                         SUM, SUMSQ, bngP, bnbP, (L > 0) ? 1 : 0,
                                         Qh, KV, Rh);
        k_attn<<<ATTNGRID, 256, 0, stream>>>(srclat, Qh, KV, We, Rh, Wb,
                                             tW, tb, rowptr, deg,
                                             H32, partials, N);
        k_statred<<<64, 256, 0, stream>>>(partials, SUM, SUMSQ, ATTNGRID);
    }

    // embedding MLP (split for occupancy): H32 -> Y1(Qbuf) -> Y2(Abuf) -> X3(Rbuf)
    k_mlp1<<<512, 256, 0, stream>>>(H32, SUM, SUMSQ,
                                    (const float*)d_in[31] + 3 * 32,
                                    (const float*)d_in[32] + 3 * 32,
                                    (const float*)d_in[33], (const float*)d_in[34],
                                    Y1f, (unsigned int*)small, N);
    k_mlp2<<<512, 256, 0, stream>>>(Y1f, (const float*)d_in[35], (const float*)d_in[36],
                                    Y2f, N);
    k_mlp3<<<512, 256, 0, stream>>>(Y2f, (const float*)d_in[37], (const float*)d_in[38],
                                    X3f, N);
    // head
    k_head1<<<ng, 256, 0, stream>>>(X3f, (const float*)d_in[39], (const float*)d_in[40],
                                    active, out, slot1, m1, N);
    k_head2<<<1, 64, 0, stream>>>(X3f, (const float*)d_in[41], (const float*)d_in[42],
                                  slot1, tvec, a1buf);
    k_head3<<<ng, 256, 0, stream>>>(X3f, tvec, active, a1buf, out + N, slot2, m2, N);
    k_sumexp<<<ng, 256, 0, stream>>>(out, out + N, m1, m2, se, N);
    k_final<<<1, 1, 0, stream>>>(out, out + N, slot2, a1buf, m1, m2, se, out + 2 * N, N);
}

// Round 23
// 797.713 us; speedup vs baseline: 2.7558x; 1.0007x over previous
//
#include <hip/hip_runtime.h>
#include <hip/hip_fp16.h>
#include <cstdint>
#include <math.h>

typedef _Float16 h2 __attribute__((ext_vector_type(2)));

__device__ __forceinline__ h2 f2h2(float a, float b) {
    h2 r; r.x = (_Float16)a; r.y = (_Float16)b; return r;
}
__device__ __forceinline__ float fdot2f(h2 a, h2 b, float c) {
    return __builtin_amdgcn_fdot2(a, b, c, false);
}

// ---------------------------------------------------------------------------
// Threefry-2x32-20, exactly as JAX lowers it.
// ---------------------------------------------------------------------------
__device__ __forceinline__ uint32_t rotl32(uint32_t x, uint32_t n) {
    return (x << n) | (x >> (32u - n));
}

__device__ __forceinline__ void tf2x32(uint32_t k0, uint32_t k1,
                                       uint32_t x0, uint32_t x1,
                                       uint32_t& o0, uint32_t& o1) {
    uint32_t k2 = k0 ^ k1 ^ 0x1BD11BDAu;
    x0 += k0; x1 += k1;
    x0 += x1; x1 = rotl32(x1, 13); x1 ^= x0;
    x0 += x1; x1 = rotl32(x1, 15); x1 ^= x0;
    x0 += x1; x1 = rotl32(x1, 26); x1 ^= x0;
    x0 += x1; x1 = rotl32(x1, 6);  x1 ^= x0;
    x0 += k1; x1 += k2 + 1u;
    x0 += x1; x1 = rotl32(x1, 17); x1 ^= x0;
    x0 += x1; x1 = rotl32(x1, 29); x1 ^= x0;
    x0 += x1; x1 = rotl32(x1, 16); x1 ^= x0;
    x0 += x1; x1 = rotl32(x1, 24); x1 ^= x0;
    x0 += k2; x1 += k0 + 2u;
    x0 += x1; x1 = rotl32(x1, 13); x1 ^= x0;
    x0 += x1; x1 = rotl32(x1, 15); x1 ^= x0;
    x0 += x1; x1 = rotl32(x1, 26); x1 ^= x0;
    x0 += x1; x1 = rotl32(x1, 6);  x1 ^= x0;
    x0 += k0; x1 += k1 + 3u;
    x0 += x1; x1 = rotl32(x1, 17); x1 ^= x0;
    x0 += x1; x1 = rotl32(x1, 29); x1 ^= x0;
    x0 += x1; x1 = rotl32(x1, 16); x1 ^= x0;
    x0 += x1; x1 = rotl32(x1, 24); x1 ^= x0;
    x0 += k1; x1 += k2 + 4u;
    x0 += x1; x1 = rotl32(x1, 13); x1 ^= x0;
    x0 += x1; x1 = rotl32(x1, 15); x1 ^= x0;
    x0 += x1; x1 = rotl32(x1, 26); x1 ^= x0;
    x0 += x1; x1 = rotl32(x1, 6);  x1 ^= x0;
    x0 += k2; x1 += k0 + 5u;
    o0 = x0; o1 = x1;
}

__device__ float gumbel_at(int n, int which, int N) {
    uint32_t a0, a1, b0, b1;
    tf2x32(0u, 42u, 0u, 2u, a0, a1);   // constant-folded by compiler
    tf2x32(0u, 42u, 1u, 3u, b0, b1);
    uint32_t gk0 = which ? a1 : a0;
    uint32_t gk1 = which ? b1 : b0;
    int half = N >> 1;
    uint32_t o0, o1, bits;
    if (n < half) { tf2x32(gk0, gk1, (uint32_t)n, (uint32_t)(n + half), o0, o1); bits = o0; }
    else          { tf2x32(gk0, gk1, (uint32_t)(n - half), (uint32_t)n, o0, o1); bits = o1; }
    float f = __uint_as_float((bits >> 9) | 0x3F800000u) - 1.0f;
    float u = fmaxf(1.17549435e-38f, f);
    return -logf(-logf(u));
}

__device__ __forceinline__ uint32_t fmono(float f) {
    uint32_t b = __float_as_uint(f);
    return (b & 0x80000000u) ? ~b : (b | 0x80000000u);
}
__device__ __forceinline__ float funmono(uint32_t u) {
    uint32_t b = (u & 0x80000000u) ? (u & 0x7FFFFFFFu) : ~u;
    return __uint_as_float(b);
}

#define NEGF (-1e9f)
#define ATTNGRID 2048  /* persistent attn blocks */

// ---------------------------------------------------------------------------
// CSR build
// ---------------------------------------------------------------------------
__global__ void k_hist(const int* __restrict__ dstp, int* __restrict__ deg, int E) {
    int e = blockIdx.x * 256 + threadIdx.x;
    if (e < E) atomicAdd(&deg[dstp[e]], 1);
}

__global__ void k_scan1(const int* __restrict__ deg, int* __restrict__ bsum, int N) {
    __shared__ int s[256];
    int i = blockIdx.x * 256 + threadIdx.x;
    s[threadIdx.x] = (i < N) ? deg[i] : 0;
    __syncthreads();
    for (int st = 128; st > 0; st >>= 1) {
        if (threadIdx.x < st) s[threadIdx.x] += s[threadIdx.x + st];
        __syncthreads();
    }
    if (threadIdx.x == 0) bsum[blockIdx.x] = s[0];
}

__global__ void k_scan2(int* __restrict__ bsum, int nb) {
    __shared__ int s[256];
    int i = threadIdx.x;
    int v = (i < nb) ? bsum[i] : 0;
    s[i] = v;
    __syncthreads();
    for (int st = 1; st < 256; st <<= 1) {
        int t = (i >= st) ? s[i - st] : 0;
        __syncthreads();
        s[i] += t;
        __syncthreads();
    }
    if (i < nb) bsum[i] = s[i] - v;  // exclusive
}

__global__ void k_scan3(const int* __restrict__ deg, const int* __restrict__ bsum,
                        int* __restrict__ rowptr, int* __restrict__ cursor, int N) {
    __shared__ int s[256];
    int i = blockIdx.x * 256 + threadIdx.x;
    int v = (i < N) ? deg[i] : 0;
    s[threadIdx.x] = v;
    __syncthreads();
    for (int st = 1; st < 256; st <<= 1) {
        int t = (threadIdx.x >= st) ? s[threadIdx.x - st] : 0;
        __syncthreads();
        s[threadIdx.x] += t;
        __syncthreads();
    }
    int excl = s[threadIdx.x] - v + bsum[blockIdx.x];
    if (i < N) { rowptr[i] = excl; cursor[i] = excl; }
}

__global__ void k_fill(const int* __restrict__ dstp, const int* __restrict__ srcp,
                       const float* __restrict__ lat, int* __restrict__ cursor,
                       int2* __restrict__ srclat, int E) {
    int e = blockIdx.x * 256 + threadIdx.x;
    if (e < E) {
        int pos = atomicAdd(&cursor[dstp[e]], 1);
        srclat[pos] = make_int2(srcp[e], __float_as_int(lat[e]));
    }
}

// ---------------------------------------------------------------------------
// k_qkvr: batched GEMV via fp16 dot2 (fp32 accum). Weights in LDS as half2
// d-pairs (~37 KB -> 4 blocks/CU; grid 1024 exposes it). BN fused into
// x-staging. Outputs FP16: Q (128h), interleaved KV (256h), R (128h).
// ---------------------------------------------------------------------------
__global__ __launch_bounds__(512, 4) void k_qkvr(
        const float* __restrict__ xin, const float* __restrict__ nt,
        const float* __restrict__ rq, int din, int N,
        const float* __restrict__ Wq, const float* __restrict__ bq,
        const float* __restrict__ Wk, const float* __restrict__ bk,
        const float* __restrict__ Wv, const float* __restrict__ bv,
        const float* __restrict__ Ws, const float* __restrict__ bs,
        const double* __restrict__ SUM, const double* __restrict__ SUMSQ,
        const float* __restrict__ bng, const float* __restrict__ bnb,
        int applyBN,
        __half* __restrict__ Q, __half* __restrict__ KV, __half* __restrict__ R) {
    __shared__ h2 w2[4][16 * 128];     // 32 KB max
    __shared__ float bias[4][128];
    __shared__ h2 xs2[32][17];
    __shared__ float sscale[32], sshift[32];
    int t = threadIdx.x;
    int dpCount = din >> 1;            // 16 or 1
    for (int i = t; i < dpCount * 128; i += 512) {
        int dp = i >> 7, j = i & 127;
        w2[0][i] = f2h2(Wq[(size_t)(2 * dp) * 128 + j], Wq[(size_t)(2 * dp + 1) * 128 + j]);
        w2[1][i] = f2h2(Wk[(size_t)(2 * dp) * 128 + j], Wk[(size_t)(2 * dp + 1) * 128 + j]);
        w2[2][i] = f2h2(Wv[(size_t)(2 * dp) * 128 + j], Wv[(size_t)(2 * dp + 1) * 128 + j]);
        w2[3][i] = f2h2(Ws[(size_t)(2 * dp) * 128 + j], Ws[(size_t)(2 * dp + 1) * 128 + j]);
    }
    if (t < 128) {
        bias[0][t] = bq[t]; bias[1][t] = bk[t]; bias[2][t] = bv[t]; bias[3][t] = bs[t];
    }
    if (t < 32) {
        if (applyBN) {
            double m = SUM[t] / N;
            double v = SUMSQ[t] / N - m * m;
            float inv = rsqrtf((float)v + 1e-5f);
            float sc = inv * bng[t];
            sscale[t] = sc;
            sshift[t] = bnb[t] - (float)m * sc;
        } else {
            sscale[t] = 1.f; sshift[t] = 0.f;
        }
    }
    int quad = t & 31;
    int sub = t >> 5;   // 0..15, two nodes each
    int dpsh = (din == 32) ? 4 : 0;
    int tiles = (N + 31) >> 5;
    for (int tile = blockIdx.x; tile < tiles; tile += gridDim.x) {
        int base = tile << 5;
        __syncthreads();
        for (int i = t; i < 32 * dpCount; i += 512) {
            int nl = i >> dpsh, dp = i & (dpCount - 1);
            int nn = base + nl;
            float x0 = 0.f, x1 = 0.f;
            if (nn < N) {
                if (din == 2) { x0 = nt[nn]; x1 = rq[nn]; }
                else {
                    x0 = xin[(size_t)nn * din + 2 * dp];
                    x1 = xin[(size_t)nn * din + 2 * dp + 1];
                }
            }
            x0 = x0 * sscale[2 * dp] + sshift[2 * dp];
            x1 = x1 * sscale[2 * dp + 1] + sshift[2 * dp + 1];
            xs2[nl][dp] = f2h2(x0, x1);
        }
        __syncthreads();
        float acc[4][2][4];  // [mat][node][comp]
#pragma unroll
        for (int m = 0; m < 4; ++m)
#pragma unroll
            for (int k = 0; k < 2; ++k)
#pragma unroll
                for (int c = 0; c < 4; ++c) acc[m][k][c] = bias[m][quad * 4 + c];
        for (int dp = 0; dp < dpCount; ++dp) {
            h2 xv0 = xs2[sub * 2 + 0][dp];
            h2 xv1 = xs2[sub * 2 + 1][dp];
#pragma unroll
            for (int m = 0; m < 4; ++m) {
                const h2* wp = &w2[m][dp * 128 + quad * 4];
                h2 wa = wp[0], wb = wp[1], wc = wp[2], wd = wp[3];
                acc[m][0][0] = fdot2f(xv0, wa, acc[m][0][0]);
                acc[m][0][1] = fdot2f(xv0, wb, acc[m][0][1]);
                acc[m][0][2] = fdot2f(xv0, wc, acc[m][0][2]);
                acc[m][0][3] = fdot2f(xv0, wd, acc[m][0][3]);
                acc[m][1][0] = fdot2f(xv1, wa, acc[m][1][0]);
                acc[m][1][1] = fdot2f(xv1, wb, acc[m][1][1]);
                acc[m][1][2] = fdot2f(xv1, wc, acc[m][1][2]);
                acc[m][1][3] = fdot2f(xv1, wd, acc[m][1][3]);
            }
        }
#pragma unroll
        for (int k = 0; k < 2; ++k) {
            int n = base + sub * 2 + k;
            if (n < N) {
                *(__half2*)&Q[(size_t)n * 128 + quad * 4 + 0] =
                    __floats2half2_rn(acc[0][k][0], acc[0][k][1]);
                *(__half2*)&Q[(size_t)n * 128 + quad * 4 + 2] =
                    __floats2half2_rn(acc[0][k][2], acc[0][k][3]);
                *(__half2*)&KV[(size_t)n * 256 + quad * 4 + 0] =
                    __floats2half2_rn(acc[1][k][0], acc[1][k][1]);
                *(__half2*)&KV[(size_t)n * 256 + quad * 4 + 2] =
                    __floats2half2_rn(acc[1][k][2], acc[1][k][3]);
                *(__half2*)&KV[(size_t)n * 256 + 128 + quad * 4 + 0] =
                    __floats2half2_rn(acc[2][k][0], acc[2][k][1]);
                *(__half2*)&KV[(size_t)n * 256 + 128 + quad * 4 + 2] =
                    __floats2half2_rn(acc[2][k][2], acc[2][k][3]);
                *(__half2*)&R[(size_t)n * 128 + quad * 4 + 0] =
                    __floats2half2_rn(acc[3][k][0], acc[3][k][1]);
                *(__half2*)&R[(size_t)n * 128 + quad * 4 + 2] =
                    __floats2half2_rn(acc[3][k][2], acc[3][k][3]);
            }
        }
    }
}

// ---------------------------------------------------------------------------
// k_attn: PURE attention (de-fused). Persistent, wave-independent striding,
// fp16 dot2, algebraic We folding, cross-node prefetch. Writes A in fp16.
// No LDS, no barriers, no stats.
// ---------------------------------------------------------------------------
__global__ __launch_bounds__(256) void k_attn(
        const int2* __restrict__ srclat,
        const __half* __restrict__ Q, const __half* __restrict__ KV,
        const float* __restrict__ We,
        const __half* __restrict__ R, const float* __restrict__ Wb,
        const int* __restrict__ rowptr, const int* __restrict__ deg,
        __half* __restrict__ A, int N) {
    int t = threadIdx.x;
    int wvid = t >> 6;
    int l64 = t & 63;
    int slot = l64 >> 5;
    int lane = l64 & 31;
    const float4 we4 = *(const float4*)&We[lane * 4];
    h2 weh0 = f2h2(we4.x, we4.y), weh1 = f2h2(we4.z, we4.w);
    const float4 wb0 = *(const float4*)&Wb[lane * 4];
    const float4 wb1 = *(const float4*)&Wb[128 + lane * 4];
    const float4 wb2 = *(const float4*)&Wb[256 + lane * 4];
    h2 zeroH; zeroH.x = (_Float16)0.f; zeroH.y = (_Float16)0.f;

    int waveGlobal = blockIdx.x * 4 + wvid;
    int totalWaves = gridDim.x * 4;

    // prefetch the first node's per-node data
    h2 pq0 = zeroH, pq1 = zeroH;
    __half2 pr0 = __floats2half2_rn(0.f, 0.f), pr1 = pr0;
    int pstart = 0, pd = 0;
    if (waveGlobal < N) {
        const h2* qp = (const h2*)(Q + (size_t)waveGlobal * 128 + lane * 4);
        pq0 = qp[0]; pq1 = qp[1];
        const __half2* rp = (const __half2*)(R + (size_t)waveGlobal * 128 + lane * 4);
        pr0 = rp[0]; pr1 = rp[1];
        pstart = rowptr[waveGlobal];
        pd = deg[waveGlobal];
    }

    for (int n = waveGlobal; n < N; n += totalWaves) {
        h2 qh0 = pq0, qh1 = pq1;
        __half2 r0h = pr0, r1h = pr1;
        int start = pstart, d = pd;

        // issue NEXT node's loads now; waits land after this node's work
        int nn = n + totalWaves;
        if (nn < N) {
            const h2* qp = (const h2*)(Q + (size_t)nn * 128 + lane * 4);
            pq0 = qp[0]; pq1 = qp[1];
            const __half2* rp = (const __half2*)(R + (size_t)nn * 128 + lane * 4);
            pr0 = rp[0]; pr1 = rp[1];
            pstart = rowptr[nn];
            pd = deg[nn];
        }

        float qwe = fdot2f(qh0, weh0, fdot2f(qh1, weh1, 0.f));
        qwe += __shfl_xor(qwe, 1); qwe += __shfl_xor(qwe, 2); qwe += __shfl_xor(qwe, 4);

        float m = -INFINITY, den = 0.f, plsum = 0.f;
        float nx = 0.f, ny = 0.f, nz = 0.f, nw = 0.f;

        int idx = slot;
        bool have = idx < d;
        float l0 = 0.f;
        h2 k0a = zeroH, k0b = zeroH, v0a = zeroH, v0b = zeroH;
        if (have) {
            int2 sl = srclat[start + idx];
            l0 = __int_as_float(sl.y);
            const h2* kp = (const h2*)(KV + (size_t)sl.x * 256 + lane * 4);
            const h2* vp = (const h2*)(KV + (size_t)sl.x * 256 + 128 + lane * 4);
            k0a = kp[0]; k0b = kp[1]; v0a = vp[0]; v0b = vp[1];
        }
        while (have) {
            int idx2 = idx + 2;
            bool have2 = idx2 < d;
            float l1 = 0.f;
            h2 k1a = zeroH, k1b = zeroH, v1a = zeroH, v1b = zeroH;
            if (have2) {   // issue next gathers BEFORE current math
                int2 sl = srclat[start + idx2];
                l1 = __int_as_float(sl.y);
                const h2* kp = (const h2*)(KV + (size_t)sl.x * 256 + lane * 4);
                const h2* vp = (const h2*)(KV + (size_t)sl.x * 256 + 128 + lane * 4);
                k1a = kp[0]; k1b = kp[1]; v1a = vp[0]; v1b = vp[1];
            }

            float t0 = fdot2f(qh0, k0a, fdot2f(qh1, k0b, 0.f));
            t0 += __shfl_xor(t0, 1); t0 += __shfl_xor(t0, 2); t0 += __shfl_xor(t0, 4);
            float alpha = fmaf(l0, qwe, t0) * 0.17677669529663687f;

            float mn = fmaxf(m, alpha);
            float sc = __expf(m - mn);
            float p = __expf(alpha - mn);
            nx = nx * sc + p * (float)v0a.x;
            ny = ny * sc + p * (float)v0a.y;
            nz = nz * sc + p * (float)v0b.x;
            nw = nw * sc + p * (float)v0b.y;
            plsum = plsum * sc + p * l0;
            den = den * sc + p;
            m = mn;

            idx = idx2; l0 = l1;
            k0a = k1a; k0b = k1b; v0a = v1a; v0b = v1b;
            have = have2;
        }

        float mo = __shfl_xor(m, 32);
        float mf = fmaxf(m, mo);
        float myscale = (m == -INFINITY) ? 0.f : __expf(m - mf);
        nx *= myscale; ny *= myscale; nz *= myscale; nw *= myscale;
        den *= myscale; plsum *= myscale;
        nx += __shfl_xor(nx, 32); ny += __shfl_xor(ny, 32);
        nz += __shfl_xor(nz, 32); nw += __shfl_xor(nw, 32);
        den += __shfl_xor(den, 32); plsum += __shfl_xor(plsum, 32);
        float inv = 1.f / (den + 1e-16f);
        float ox = fmaf(plsum, we4.x, nx) * inv;
        float oy = fmaf(plsum, we4.y, ny) * inv;
        float oz = fmaf(plsum, we4.z, nz) * inv;
        float ow = fmaf(plsum, we4.w, nw) * inv;

        float2 ra = __half22float2(r0h), rb = __half22float2(r1h);
        float g = ox * wb0.x + ra.x * wb1.x + (ox - ra.x) * wb2.x
                + oy * wb0.y + ra.y * wb1.y + (oy - ra.y) * wb2.y
                + oz * wb0.z + rb.x * wb1.z + (oz - rb.x) * wb2.z
                + ow * wb0.w + rb.y * wb1.w + (ow - rb.y) * wb2.w;
        g += __shfl_xor(g, 1); g += __shfl_xor(g, 2); g += __shfl_xor(g, 4);
        g += __shfl_xor(g, 8); g += __shfl_xor(g, 16);
        float beta = 1.0f / (1.0f + __expf(-g));

        if (slot == 0) {
            float a0 = beta * ra.x + (1.0f - beta) * ox;
            float a1 = beta * ra.y + (1.0f - beta) * oy;
            float a2 = beta * rb.x + (1.0f - beta) * oz;
            float a3 = beta * rb.y + (1.0f - beta) * ow;
            *(__half2*)&A[(size_t)n * 128 + lane * 4 + 0] = __floats2half2_rn(a0, a1);
            *(__half2*)&A[(size_t)n * 128 + lane * 4 + 2] = __floats2half2_rn(a2, a3);
        }
    }
}

// ---------------------------------------------------------------------------
// k_linstats: Y = relu(A(fp16) @ tW + tb) via fp16 dot2. 64-node tile per
// block; A staged TRANSPOSED as h2 d-pairs (xsT[dp][node]); tW in LDS as
// h2 d-pairs. quad=t&7 (4 cols), sub=t>>3 (2 nodes). Per-block stat
// partials (shuffle + LDS reduce, plain store).
// ---------------------------------------------------------------------------
__global__ __launch_bounds__(256) void k_linstats(
        const __half* __restrict__ A, const float* __restrict__ tW,
        const float* __restrict__ tb, float* __restrict__ H32,
        double* __restrict__ partials, int N) {
    __shared__ h2 w2l[64 * 32];       // 8 KB: (tW[2dp][j], tW[2dp+1][j])
    __shared__ float bias[32];
    __shared__ h2 xsT[64][66];        // ~16.9 KB, dp-major
    __shared__ double sp1[4][8][4], sp2[4][8][4];
    int t = threadIdx.x;
    for (int i = t; i < 64 * 32; i += 256) {
        int dp = i >> 5, j = i & 31;
        w2l[i] = f2h2(tW[(size_t)(2 * dp) * 32 + j], tW[(size_t)(2 * dp + 1) * 32 + j]);
    }
    if (t < 32) bias[t] = tb[t];
    int quad = t & 7;      // 8 quads -> 32 cols
    int sub = t >> 3;      // 32 subs x 2 nodes = 64 nodes
    int base = blockIdx.x << 6;

    // stage 64x128h A-tile transposed: i = t + 256k (k<4); nl = i>>4 (node),
    // g8 = i&15 (group of 8 halfs = 4 dp). Global read = 16B per thread.
    __syncthreads();
#pragma unroll
    for (int k = 0; k < 4; ++k) {
        int i = t + 256 * k;
        int nl = i >> 4, g8 = i & 15;
        int n = base + nl;
        h2 hv[4];
        if (n < N) {
            const h2* ap = (const h2*)(A + (size_t)n * 128 + g8 * 8);
            hv[0] = ap[0]; hv[1] = ap[1]; hv[2] = ap[2]; hv[3] = ap[3];
        } else {
            h2 z; z.x = (_Float16)0.f; z.y = (_Float16)0.f;
            hv[0] = z; hv[1] = z; hv[2] = z; hv[3] = z;
        }
        xsT[g8 * 4 + 0][nl] = hv[0];
        xsT[g8 * 4 + 1][nl] = hv[1];
        xsT[g8 * 4 + 2][nl] = hv[2];
        xsT[g8 * 4 + 3][nl] = hv[3];
    }
    __syncthreads();

    float acc[2][4];
#pragma unroll
    for (int k = 0; k < 2; ++k)
#pragma unroll
        for (int c = 0; c < 4; ++c) acc[k][c] = bias[quad * 4 + c];
    for (int dp = 0; dp < 64; ++dp) {
        h2 x0 = xsT[dp][sub * 2 + 0];
        h2 x1 = xsT[dp][sub * 2 + 1];
        const h2* wp = &w2l[dp * 32 + quad * 4];
        h2 wa = wp[0], wb = wp[1], wc = wp[2], wd = wp[3];
        acc[0][0] = fdot2f(x0, wa, acc[0][0]);
        acc[0][1] = fdot2f(x0, wb, acc[0][1]);
        acc[0][2] = fdot2f(x0, wc, acc[0][2]);
        acc[0][3] = fdot2f(x0, wd, acc[0][3]);
        acc[1][0] = fdot2f(x1, wa, acc[1][0]);
        acc[1][1] = fdot2f(x1, wb, acc[1][1]);
        acc[1][2] = fdot2f(x1, wc, acc[1][2]);
        acc[1][3] = fdot2f(x1, wd, acc[1][3]);
    }
    double s1[4] = {0, 0, 0, 0}, s2[4] = {0, 0, 0, 0};
#pragma unroll
    for (int k = 0; k < 2; ++k) {
        int n = base + sub * 2 + k;
        if (n < N) {
            float4 yv;
            yv.x = fmaxf(acc[k][0], 0.f); yv.y = fmaxf(acc[k][1], 0.f);
            yv.z = fmaxf(acc[k][2], 0.f); yv.w = fmaxf(acc[k][3], 0.f);
            *(float4*)&H32[(size_t)n * 32 + quad * 4] = yv;
            s1[0] += yv.x; s1[1] += yv.y; s1[2] += yv.z; s1[3] += yv.w;
            s2[0] += (double)yv.x * yv.x; s2[1] += (double)yv.y * yv.y;
            s2[2] += (double)yv.z * yv.z; s2[3] += (double)yv.w * yv.w;
        }
    }
    // reduce over subs within each wave (quad preserved under xor >= 8)
#pragma unroll
    for (int c = 0; c < 4; ++c) {
        s1[c] += __shfl_xor(s1[c], 8);  s2[c] += __shfl_xor(s2[c], 8);
        s1[c] += __shfl_xor(s1[c], 16); s2[c] += __shfl_xor(s2[c], 16);
        s1[c] += __shfl_xor(s1[c], 32); s2[c] += __shfl_xor(s2[c], 32);
    }
    __syncthreads();
    int wave = t >> 6;
    if ((t & 63) < 8) {
#pragma unroll
        for (int c = 0; c < 4; ++c) { sp1[wave][quad][c] = s1[c]; sp2[wave][quad][c] = s2[c]; }
    }
    __syncthreads();
    if (t < 32) {
        int q = t >> 2, c = t & 3;
        double a1 = 0, a2 = 0;
#pragma unroll
        for (int wv = 0; wv < 4; ++wv) { a1 += sp1[wv][q][c]; a2 += sp2[wv][q][c]; }
        partials[(size_t)blockIdx.x * 64 + t] = a1;
        partials[(size_t)blockIdx.x * 64 + 32 + t] = a2;
    }
}

// ---------------------------------------------------------------------------
// Single-kernel stat reduction: block = one output column (64 blocks).
// ---------------------------------------------------------------------------
__global__ void k_statred(const double* __restrict__ partials,
                          double* __restrict__ SUM, double* __restrict__ SUMSQ,
                          int nblocks) {
    __shared__ double s[256];
    int col = blockIdx.x;   // 0..63
    double a = 0;
    for (int b = threadIdx.x; b < nblocks; b += 256)
        a += partials[(size_t)b * 64 + col];
    s[threadIdx.x] = a;
    __syncthreads();
    for (int st = 128; st > 0; st >>= 1) {
        if (threadIdx.x < st) s[threadIdx.x] += s[threadIdx.x + st];
        __syncthreads();
    }
    if (threadIdx.x == 0) {
        if (col < 32) SUM[col] = s[0];
        else SUMSQ[col - 32] = s[0];
    }
}

// ---------------------------------------------------------------------------
// k_mlp1: BN affine + 32->128 relu. Block 0 zero-inits head scratch.
// ---------------------------------------------------------------------------
__global__ __launch_bounds__(256) void k_mlp1(
        const float* __restrict__ H32,
        const double* __restrict__ SUM, const double* __restrict__ SUMSQ,
        const float* __restrict__ bng, const float* __restrict__ bnb,
        const float* __restrict__ W1, const float* __restrict__ b1,
        float* __restrict__ Y1, unsigned int* __restrict__ smallbuf, int N) {
    __shared__ float w1[32 * 128];
    __shared__ float sb1[128];
    __shared__ float sscale[32], sshift[32];
    __shared__ float xs[32][36];
    int t = threadIdx.x;
    if (blockIdx.x == 0 && t < 16) smallbuf[t] = 0u;  // zero 64 B head scratch
    for (int i = t; i < 32 * 128; i += 256) w1[i] = W1[i];
    if (t < 128) sb1[t] = b1[t];
    if (t < 32) {
        double m = SUM[t] / N;
        double v = SUMSQ[t] / N - m * m;
        float inv = rsqrtf((float)v + 1e-5f);
        float sc = inv * bng[t];
        sscale[t] = sc;
        sshift[t] = bnb[t] - (float)m * sc;
    }
    int quad = t & 31, sub = t >> 5;
    int tiles = (N + 31) >> 5;
    for (int tile = blockIdx.x; tile < tiles; tile += gridDim.x) {
        int base = tile << 5;
        __syncthreads();
        {
            int nl = t >> 3, q = t & 7;
            int n = base + nl;
            float4 xv = make_float4(0.f, 0.f, 0.f, 0.f);
            if (n < N) xv = *(const float4*)&H32[(size_t)n * 32 + q * 4];
            xs[nl][q * 4 + 0] = xv.x * sscale[q * 4 + 0] + sshift[q * 4 + 0];
            xs[nl][q * 4 + 1] = xv.y * sscale[q * 4 + 1] + sshift[q * 4 + 1];
            xs[nl][q * 4 + 2] = xv.z * sscale[q * 4 + 2] + sshift[q * 4 + 2];
            xs[nl][q * 4 + 3] = xv.w * sscale[q * 4 + 3] + sshift[q * 4 + 3];
        }
        __syncthreads();
        float a[4][4];
#pragma unroll
        for (int k = 0; k < 4; ++k)
#pragma unroll
            for (int c = 0; c < 4; ++c) a[k][c] = sb1[quad * 4 + c];
        for (int d = 0; d < 32; ++d) {
            float4 w4 = *(const float4*)&w1[d * 128 + quad * 4];
#pragma unroll
            for (int k = 0; k < 4; ++k) {
                float x = xs[sub * 4 + k][d];
                a[k][0] = fmaf(x, w4.x, a[k][0]);
                a[k][1] = fmaf(x, w4.y, a[k][1]);
                a[k][2] = fmaf(x, w4.z, a[k][2]);
                a[k][3] = fmaf(x, w4.w, a[k][3]);
            }
        }
#pragma unroll
        for (int k = 0; k < 4; ++k) {
            int n = base + sub * 4 + k;
            if (n < N) {
                float4 yv;
                yv.x = fmaxf(a[k][0], 0.f); yv.y = fmaxf(a[k][1], 0.f);
                yv.z = fmaxf(a[k][2], 0.f); yv.w = fmaxf(a[k][3], 0.f);
                *(float4*)&Y1[(size_t)n * 128 + quad * 4] = yv;
            }
        }
    }
}

// ---------------------------------------------------------------------------
// k_mlp2: 128->64 relu.
// ---------------------------------------------------------------------------
__global__ __launch_bounds__(256) void k_mlp2(
        const float* __restrict__ Y1, const float* __restrict__ W2,
        const float* __restrict__ b2, float* __restrict__ Y2, int N) {
    __shared__ float w2f[128 * 64];
    __shared__ float sb2[64];
    __shared__ float xs[32][132];
    int t = threadIdx.x;
    for (int i = t; i < 128 * 64; i += 256) w2f[i] = W2[i];
    if (t < 64) sb2[t] = b2[t];
    int quad = t & 15, sub = t >> 4;
    int tiles = (N + 31) >> 5;
    for (int tile = blockIdx.x; tile < tiles; tile += gridDim.x) {
        int base = tile << 5;
        __syncthreads();
#pragma unroll
        for (int k = 0; k < 4; ++k) {
            int i = t + 256 * k;
            int nl = i >> 5, q = i & 31;
            int n = base + nl;
            float4 xv = make_float4(0.f, 0.f, 0.f, 0.f);
            if (n < N) xv = *(const float4*)&Y1[(size_t)n * 128 + q * 4];
            *(float4*)&xs[nl][q * 4] = xv;
        }
        __syncthreads();
        float a[2][4];
#pragma unroll
        for (int k = 0; k < 2; ++k)
#pragma unroll
            for (int c = 0; c < 4; ++c) a[k][c] = sb2[quad * 4 + c];
        for (int d = 0; d < 128; ++d) {
            float4 w4 = *(const float4*)&w2f[d * 64 + quad * 4];
#pragma unroll
            for (int k = 0; k < 2; ++k) {
                float x = xs[sub * 2 + k][d];
                a[k][0] = fmaf(x, w4.x, a[k][0]);
                a[k][1] = fmaf(x, w4.y, a[k][1]);
                a[k][2] = fmaf(x, w4.z, a[k][2]);
                a[k][3] = fmaf(x, w4.w, a[k][3]);
            }
        }
#pragma unroll
        for (int k = 0; k < 2; ++k) {
            int n = base + sub * 2 + k;
            if (n < N) {
                float4 yv;
                yv.x = fmaxf(a[k][0], 0.f); yv.y = fmaxf(a[k][1], 0.f);
                yv.z = fmaxf(a[k][2], 0.f); yv.w = fmaxf(a[k][3], 0.f);
                *(float4*)&Y2[(size_t)n * 64 + quad * 4] = yv;
            }
        }
    }
}

// ---------------------------------------------------------------------------
// k_mlp3: 64->64 (no relu), pure GEMV.
// ---------------------------------------------------------------------------
__global__ __launch_bounds__(256) void k_mlp3(
        const float* __restrict__ Y2, const float* __restrict__ W3,
        const float* __restrict__ b3, float* __restrict__ X3, int N) {
    __shared__ float w3[64 * 64];
    __shared__ float sb3[64];
    __shared__ float xs[32][68];
    int t = threadIdx.x;
    for (int i = t; i < 64 * 64; i += 256) w3[i] = W3[i];
    if (t < 64) sb3[t] = b3[t];
    int quad = t & 15, sub = t >> 4;
    int tiles = (N + 31) >> 5;
    for (int tile = blockIdx.x; tile < tiles; tile += gridDim.x) {
        int base = tile << 5;
        __syncthreads();
#pragma unroll
        for (int k = 0; k < 2; ++k) {
            int i = t + 256 * k;
            int nl = i >> 4, q = i & 15;
            int n = base + nl;
            float4 xv = make_float4(0.f, 0.f, 0.f, 0.f);
            if (n < N) xv = *(const float4*)&Y2[(size_t)n * 64 + q * 4];
            *(float4*)&xs[nl][q * 4] = xv;
        }
        __syncthreads();
        float a[2][4];
#pragma unroll
        for (int k = 0; k < 2; ++k)
#pragma unroll
            for (int c = 0; c < 4; ++c) a[k][c] = sb3[quad * 4 + c];
        for (int d = 0; d < 64; ++d) {
            float4 w4 = *(const float4*)&w3[d * 64 + quad * 4];
#pragma unroll
            for (int k = 0; k < 2; ++k) {
                float x = xs[sub * 2 + k][d];
                a[k][0] = fmaf(x, w4.x, a[k][0]);
                a[k][1] = fmaf(x, w4.y, a[k][1]);
                a[k][2] = fmaf(x, w4.z, a[k][2]);
                a[k][3] = fmaf(x, w4.w, a[k][3]);
            }
        }
#pragma unroll
        for (int k = 0; k < 2; ++k) {
            int n = base + sub * 2 + k;
            if (n < N)
                *(float4*)&X3[(size_t)n * 64 + quad * 4] = *(float4*)a[k];
        }
    }
}

// ---------------------------------------------------------------------------
// Head kernels
// ---------------------------------------------------------------------------
__global__ void k_head1(const float* __restrict__ X3, const float* __restrict__ remW,
                        const float* __restrict__ remB, const int* __restrict__ active,
                        float* __restrict__ l1out, unsigned long long* __restrict__ slot1,
                        unsigned int* __restrict__ m1, int N) {
    int n = blockIdx.x * 256 + threadIdx.x;
    if (n >= N) return;
    const float* xr = X3 + (size_t)n * 64;
    float acc = remB[0];
    for (int d = 0; d < 64; d++) acc = fmaf(xr[d], remW[d], acc);
    float maskf = (active[n] == 1) ? 0.f : NEGF;
    float rm = (n < 15) ? ((maskf == 0.f) ? NEGF : 0.f) : maskf;
    float l1 = acc + rm;
    l1out[n] = l1;
    atomicMax(m1, fmono(l1));
    float z = l1 + gumbel_at(n, 0, N);
    unsigned long long p = ((unsigned long long)fmono(z) << 32) |
                           (unsigned long long)(0xFFFFFFFFu - (unsigned)n);
    atomicMax(slot1, p);
}

__global__ void k_head2(const float* __restrict__ X3, const float* __restrict__ addW,
                        const float* __restrict__ addB,
                        const unsigned long long* __restrict__ slot1,
                        float* __restrict__ tvec, int* __restrict__ a1buf) {
    int j = threadIdx.x;  // 64
    unsigned long long p = *slot1;
    int a1 = (int)(0xFFFFFFFFu - (unsigned)(p & 0xFFFFFFFFull));
    const float* xr = X3 + (size_t)a1 * 64;
    float acc = addB[j];
    for (int d = 0; d < 64; d++) acc = fmaf(xr[d], addW[d * 64 + j], acc);
    tvec[j] = tanhf(acc);
    if (j == 0) *a1buf = a1;
}

__global__ void k_head3(const float* __restrict__ X3, const float* __restrict__ tvec,
                        const int* __restrict__ active, const int* __restrict__ a1buf,
                        float* __restrict__ l2out, unsigned long long* __restrict__ slot2,
                        unsigned int* __restrict__ m2, int N) {
    int n = blockIdx.x * 256 + threadIdx.x;
    if (n >= N) return;
    const float* xr = X3 + (size_t)n * 64;
    float acc = 0.f;
    for (int d = 0; d < 64; d++) acc = fmaf(xr[d], tvec[d], acc);
    float maskf = (active[n] == 1) ? 0.f : NEGF;
    if (n == *a1buf) maskf = 0.f;
    float l2 = acc + maskf;
    l2out[n] = l2;
    atomicMax(m2, fmono(l2));
    float z = l2 + gumbel_at(n, 1, N);
    unsigned long long p = ((unsigned long long)fmono(z) << 32) |
                           (unsigned long long)(0xFFFFFFFFu - (unsigned)n);
    atomicMax(slot2, p);
}

__global__ void k_sumexp(const float* __restrict__ l1, const float* __restrict__ l2,
                         const unsigned int* __restrict__ m1, const unsigned int* __restrict__ m2,
                         float* __restrict__ se, int N) {
    int t = blockIdx.x * 256 + threadIdx.x;
    float M1 = funmono(*m1), M2 = funmono(*m2);
    float e1 = 0.f, e2 = 0.f;
    if (t < N) { e1 = expf(l1[t] - M1); e2 = expf(l2[t] - M2); }
    __shared__ float r1[256], r2[256];
    r1[threadIdx.x] = e1; r2[threadIdx.x] = e2;
    __syncthreads();
    for (int s = 128; s > 0; s >>= 1) {
        if (threadIdx.x < s) { r1[threadIdx.x] += r1[threadIdx.x + s]; r2[threadIdx.x] += r2[threadIdx.x + s]; }
        __syncthreads();
    }
    if (threadIdx.x == 0) { atomicAdd(&se[0], r1[0]); atomicAdd(&se[1], r2[0]); }
}

__global__ void k_final(const float* __restrict__ l1, const float* __restrict__ l2,
                        const unsigned long long* __restrict__ slot2,
                        const int* __restrict__ a1buf,
                        const unsigned int* __restrict__ m1, const unsigned int* __restrict__ m2,
                        const float* __restrict__ se, float* __restrict__ outTail, int N) {
    int a1 = *a1buf;
    int a2 = (int)(0xFFFFFFFFu - (unsigned)((*slot2) & 0xFFFFFFFFull));
    outTail[0] = (float)a1;
    outTail[1] = (float)a2;
    outTail[2] = l1[a1] - (funmono(*m1) + logf(se[0]));
    outTail[3] = l2[a2] - (funmono(*m2) + logf(se[1]));
}

// ---------------------------------------------------------------------------
// Host launcher
// ---------------------------------------------------------------------------
extern "C" void kernel_launch(void* const* d_in, const int* in_sizes, int n_in,
                              void* d_out, int out_size, void* d_ws, size_t ws_size,
                              hipStream_t stream) {
    const float* node_type = (const float*)d_in[0];
    const float* requests  = (const float*)d_in[1];
    const float* latency   = (const float*)d_in[2];
    const int* edge_index  = (const int*)d_in[3];
    const int* active      = (const int*)d_in[4];
    int N = in_sizes[0];
    int E = in_sizes[2];
    const int* src = edge_index;
    const int* dst = edge_index + E;
    float* out = (float*)d_out;

    char* base = (char*)d_ws;
    size_t off = 0;
    auto alloc = [&](size_t bytes) -> char* {
        char* p = base + off;
        off += (bytes + 255) & ~(size_t)255;
        return p;
    };
    char* Abuf   = alloc((size_t)N * 128 * 4);  // fp16 A; later fp32 Y2
    char* Qbuf   = alloc((size_t)N * 128 * 4);  // fp16 Q; later fp32 Y1
    __half* KV   = (__half*)alloc((size_t)N * 256 * 2); // interleaved K,V fp16
    char* Rbuf   = alloc((size_t)N * 128 * 4);  // fp16 R; later fp32 X3
    float* H32   = (float*)alloc((size_t)N * 32 * 4);
    int* deg     = (int*)alloc((size_t)N * 4);
    int* rowptr  = (int*)alloc((size_t)N * 4);
    int* cursor  = (int*)alloc((size_t)N * 4);
    int2* srclat = (int2*)alloc((size_t)E * 8);
    int* bsum    = (int*)alloc(1024 * 4);
    int lsTiles = (N + 63) / 64;
    double* partials = (double*)alloc((size_t)lsTiles * 64 * 8);
    double* SUM  = (double*)alloc(512);
    double* SUMSQ = SUM + 32;
    char* small  = alloc(1024);
    unsigned long long* slot1 = (unsigned long long*)small;
    unsigned long long* slot2 = slot1 + 1;
    unsigned int* m1 = (unsigned int*)(small + 16);
    unsigned int* m2 = m1 + 1;
    float* se = (float*)(small + 24);
    int* a1buf = (int*)(small + 32);
    float* tvec = (float*)(small + 64);

    __half* Ah = (__half*)Abuf;   float* Y2f = (float*)Abuf;
    __half* Qh = (__half*)Qbuf;   float* Y1f = (float*)Qbuf;
    __half* Rh = (__half*)Rbuf;   float* X3f = (float*)Rbuf;

    int ng = (N + 255) / 256;
    int egE = (E + 255) / 256;
    int nb = ng;

    // ---- CSR build ----
    (void)hipMemsetAsync(deg, 0, (size_t)N * 4, stream);
    k_hist<<<egE, 256, 0, stream>>>(dst, deg, E);
    k_scan1<<<nb, 256, 0, stream>>>(deg, bsum, N);
    k_scan2<<<1, 256, 0, stream>>>(bsum, nb);
    k_scan3<<<nb, 256, 0, stream>>>(deg, bsum, rowptr, cursor, N);
    k_fill<<<egE, 256, 0, stream>>>(dst, src, latency, cursor, srclat, E);

    for (int L = 0; L < 5; ++L) {
        int din = L ? 32 : 2;
        const float* xin = L ? H32 : nullptr;
        const float* Wq = L ? (const float*)d_in[19] + (size_t)(L - 1) * 4096 : (const float*)d_in[5];
        const float* bq = L ? (const float*)d_in[20] + (size_t)(L - 1) * 128  : (const float*)d_in[6];
        const float* Wk = L ? (const float*)d_in[21] + (size_t)(L - 1) * 4096 : (const float*)d_in[7];
        const float* bk = L ? (const float*)d_in[22] + (size_t)(L - 1) * 128  : (const float*)d_in[8];
        const float* Wv = L ? (const float*)d_in[23] + (size_t)(L - 1) * 4096 : (const float*)d_in[9];
        const float* bv = L ? (const float*)d_in[24] + (size_t)(L - 1) * 128  : (const float*)d_in[10];
        const float* We = L ? (const float*)d_in[25] + (size_t)(L - 1) * 128  : (const float*)d_in[11];
        const float* Ws = L ? (const float*)d_in[26] + (size_t)(L - 1) * 4096 : (const float*)d_in[12];
        const float* bs = L ? (const float*)d_in[27] + (size_t)(L - 1) * 128  : (const float*)d_in[13];
        const float* Wb = L ? (const float*)d_in[28] + (size_t)(L - 1) * 384  : (const float*)d_in[14];
        const float* tW = L ? (const float*)d_in[29] + (size_t)(L - 1) * 4096 : (const float*)d_in[15];
        const float* tb = L ? (const float*)d_in[30] + (size_t)(L - 1) * 32   : (const float*)d_in[16];
        const float* bngP = (L == 1) ? (const float*)d_in[17]
                          : (L >= 2) ? (const float*)d_in[31] + (size_t)(L - 2) * 32 : nullptr;
        const float* bnbP = (L == 1) ? (const float*)d_in[18]
                          : (L >= 2) ? (const float*)d_in[32] + (size_t)(L - 2) * 32 : nullptr;

        k_qkvr<<<1024, 512, 0, stream>>>(xin, node_type, requests, din, N,
                                         Wq, bq, Wk, bk, Wv, bv, Ws, bs,
                                         SUM, SUMSQ, bngP, bnbP, (L > 0) ? 1 : 0,
                                         Qh, KV, Rh);
        k_attn<<<ATTNGRID, 256, 0, stream>>>(srclat, Qh, KV, We, Rh, Wb,
                                             rowptr, deg, Ah, N);
        k_linstats<<<lsTiles, 256, 0, stream>>>(Ah, tW, tb, H32, partials, N);
        k_statred<<<64, 256, 0, stream>>>(partials, SUM, SUMSQ, lsTiles);
    }

    // embedding MLP (split for occupancy): H32 -> Y1(Qbuf) -> Y2(Abuf) -> X3(Rbuf)
    k_mlp1<<<512, 256, 0, stream>>>(H32, SUM, SUMSQ,
                                    (const float*)d_in[31] + 3 * 32,
                                    (const float*)d_in[32] + 3 * 32,
                                    (const float*)d_in[33], (const float*)d_in[34],
                                    Y1f, (unsigned int*)small, N);
    k_mlp2<<<512, 256, 0, stream>>>(Y1f, (const float*)d_in[35], (const float*)d_in[36],
                                    Y2f, N);
    k_mlp3<<<512, 256, 0, stream>>>(Y2f, (const float*)d_in[37], (const float*)d_in[38],
                                    X3f, N);
    // head
    k_head1<<<ng, 256, 0, stream>>>(X3f, (const float*)d_in[39], (const float*)d_in[40],
                                    active, out, slot1, m1, N);
    k_head2<<<1, 64, 0, stream>>>(X3f, (const float*)d_in[41], (const float*)d_in[42],
                                  slot1, tvec, a1buf);
    k_head3<<<ng, 256, 0, stream>>>(X3f, tvec, active, a1buf, out + N, slot2, m2, N);
    k_sumexp<<<ng, 256, 0, stream>>>(out, out + N, m1, m2, se, N);
    k_final<<<1, 1, 0, stream>>>(out, out + N, slot2, a1buf, m1, m2, se, out + 2 * N, N);
}